// Round 1
// baseline (2800.916 us; speedup 1.0000x reference)
//
#include <hip/hip_runtime.h>
#include <hip/hip_bf16.h>
#include <math.h>

#define NHEADS 4
#define DKH 256
#define DVH 512
#define SEQL 2048
#define NB 2
#define NTOK (NB*SEQL)     // 4096
#define DM 1024            // d_model
#define KDT 1024           // NHEADS*DKH
#define VDT 2048           // NHEADS*DVH

// ---------------- generic fp32 GEMM: C = scale*(A[M,K] @ B[K,N]) ----------------
__global__ __launch_bounds__(256)
void gemm_f32(const float* __restrict__ A, const float* __restrict__ B,
              float* __restrict__ C, int M, int N, int K, float scale)
{
  __shared__ __align__(16) float As[16][68];   // [k][m], +4 pad keeps float4 alignment
  __shared__ __align__(16) float Bs[16][68];   // [k][n]
  const int tid = threadIdx.x;
  const int tx = tid & 15, ty = tid >> 4;
  const int bm = blockIdx.y * 64, bn = blockIdx.x * 64;
  float acc[4][4] = {};
  for (int k0 = 0; k0 < K; k0 += 16) {
    {
      const int row = tid >> 2, kk = (tid & 3) << 2;
      const float4 a4 = *(const float4*)&A[(size_t)(bm + row) * K + k0 + kk];
      As[kk+0][row] = a4.x; As[kk+1][row] = a4.y;
      As[kk+2][row] = a4.z; As[kk+3][row] = a4.w;
    }
    {
      const int kk = tid >> 4, n = (tid & 15) << 2;
      *(float4*)&Bs[kk][n] = *(const float4*)&B[(size_t)(k0 + kk) * N + bn + n];
    }
    __syncthreads();
    #pragma unroll
    for (int kk = 0; kk < 16; ++kk) {
      const float4 a4 = *(const float4*)&As[kk][ty << 2];
      const float4 b4 = *(const float4*)&Bs[kk][tx << 2];
      const float av[4] = {a4.x, a4.y, a4.z, a4.w};
      const float bv[4] = {b4.x, b4.y, b4.z, b4.w};
      #pragma unroll
      for (int i = 0; i < 4; ++i)
        #pragma unroll
        for (int j = 0; j < 4; ++j)
          acc[i][j] += av[i] * bv[j];
    }
    __syncthreads();
  }
  #pragma unroll
  for (int i = 0; i < 4; ++i) {
    float4 o4 = make_float4(scale*acc[i][0], scale*acc[i][1], scale*acc[i][2], scale*acc[i][3]);
    *(float4*)&C[(size_t)(bm + (ty << 2) + i) * N + bn + (tx << 2)] = o4;
  }
}

// ---------------- U = x @ gk_w1  (M=4096, N=16, K=1024) ----------------
__global__ __launch_bounds__(256)
void gemm_u(const float* __restrict__ X, const float* __restrict__ W1,
            float* __restrict__ U)
{
  __shared__ float Xs[64][65];                  // [k][m] scalar access only
  __shared__ __align__(16) float W1s[64][16];   // [k][n]
  const int tid = threadIdx.x;
  const int row0 = blockIdx.x * 64;
  const int rr = tid & 63, gg = tid >> 6;       // row, col-group (4 cols)
  float acc[4] = {0.f, 0.f, 0.f, 0.f};
  for (int k0 = 0; k0 < DM; k0 += 64) {
    #pragma unroll
    for (int rep = 0; rep < 4; ++rep) {
      const int m = (tid >> 4) + rep * 16;
      const int kk = (tid & 15) << 2;
      const float4 x4 = *(const float4*)&X[(size_t)(row0 + m) * DM + k0 + kk];
      Xs[kk+0][m] = x4.x; Xs[kk+1][m] = x4.y; Xs[kk+2][m] = x4.z; Xs[kk+3][m] = x4.w;
    }
    {
      const int kk = tid >> 2, n = (tid & 3) << 2;
      *(float4*)&W1s[kk][n] = *(const float4*)&W1[(size_t)(k0 + kk) * 16 + n];
    }
    __syncthreads();
    #pragma unroll
    for (int k2 = 0; k2 < 64; ++k2) {
      const float xv = Xs[k2][rr];
      const float4 w4 = *(const float4*)&W1s[k2][gg << 2];
      acc[0] += xv * w4.x; acc[1] += xv * w4.y; acc[2] += xv * w4.z; acc[3] += xv * w4.w;
    }
    __syncthreads();
  }
  *(float4*)&U[(size_t)(row0 + rr) * 16 + (gg << 2)] =
      make_float4(acc[0], acc[1], acc[2], acc[3]);
}

// ---------------- EGK = exp(log_sigmoid(U @ gk_w2 + b2) / 16) ----------------
__device__ inline float ls_exp(float z) {
  const float ls = (z >= 0.f) ? -log1pf(expf(-z)) : (z - log1pf(expf(z)));
  return expf(ls * 0.0625f);   // /GATE_NORM(16)
}

__global__ __launch_bounds__(256)
void gate_kernel(const float* __restrict__ U, const float* __restrict__ W2,
                 const float* __restrict__ b2, float* __restrict__ EGKo)
{
  __shared__ float Us[16];
  const int row = blockIdx.x, tid = threadIdx.x;
  if (tid < 16) Us[tid] = U[row * 16 + tid];
  __syncthreads();
  const int d0 = tid << 2;
  float4 z = *(const float4*)&b2[d0];
  #pragma unroll
  for (int r = 0; r < 16; ++r) {
    const float u = Us[r];
    const float4 w4 = *(const float4*)&W2[r * 1024 + d0];
    z.x += u * w4.x; z.y += u * w4.y; z.z += u * w4.z; z.w += u * w4.w;
  }
  float4 e = make_float4(ls_exp(z.x), ls_exp(z.y), ls_exp(z.z), ls_exp(z.w));
  *(float4*)&EGKo[(size_t)row * 1024 + d0] = e;
}

// ---------------- GLA scan: S_t = diag(egk_t) S_{t-1} + k_t v_t^T ; o_t = q_t S_t
// grid: (8 dv-slices of 64 cols, 8 bh). block 256: c=tid>>2 (column), r=tid&3 (64-row group)
__global__ __launch_bounds__(256)
void gla_scan(const float* __restrict__ Q, const float* __restrict__ Kb,
              const float* __restrict__ EG, const float* __restrict__ V,
              float* __restrict__ O)
{
  const int s = blockIdx.x;          // dv slice
  const int bh = blockIdx.y;
  const int b = bh >> 2, h = bh & 3;
  const int tid = threadIdx.x;
  const int c = tid >> 2, r = tid & 3;
  __shared__ __align__(16) float EGs[4 * 68];
  __shared__ __align__(16) float KKs[4 * 68];
  __shared__ __align__(16) float QQs[4 * 68];
  __shared__ __align__(16) float VV[64];
  float S[64];
  #pragma unroll
  for (int i = 0; i < 64; ++i) S[i] = 0.f;

  const size_t qkBase = ((size_t)b * SEQL) * KDT + h * DKH;
  const size_t vBase  = ((size_t)b * SEQL) * VDT + h * DVH + s * 64;
  const int sidx = (tid >> 6) * 68 + (tid & 63);

  // prefetch t = 0
  float pe = EG[qkBase + tid];
  float pk = Kb[qkBase + tid];
  float pq = Q [qkBase + tid];
  float pv = (tid < 64) ? V[vBase + tid] : 0.f;

  for (int t = 0; t < SEQL; ++t) {
    EGs[sidx] = pe; KKs[sidx] = pk; QQs[sidx] = pq;
    if (tid < 64) VV[tid] = pv;
    __syncthreads();
    // prefetch t+1 (independent of this step's compute)
    {
      const int tn = (t + 1 < SEQL) ? t + 1 : t;
      const size_t qkRow = qkBase + (size_t)tn * KDT;
      pe = EG[qkRow + tid];
      pk = Kb[qkRow + tid];
      pq = Q [qkRow + tid];
      if (tid < 64) pv = V[vBase + (size_t)tn * VDT + tid];
    }
    const float vv = VV[c];
    float p = 0.f;
    const float* eb = &EGs[r * 68];
    const float* kb = &KKs[r * 68];
    const float* qb = &QQs[r * 68];
    #pragma unroll
    for (int ii = 0; ii < 16; ++ii) {
      const float4 e4 = *(const float4*)(eb + (ii << 2));
      const float4 k4 = *(const float4*)(kb + (ii << 2));
      const float4 q4 = *(const float4*)(qb + (ii << 2));
      const int i0 = ii << 2;
      S[i0+0] = S[i0+0] * e4.x + k4.x * vv; p += q4.x * S[i0+0];
      S[i0+1] = S[i0+1] * e4.y + k4.y * vv; p += q4.y * S[i0+1];
      S[i0+2] = S[i0+2] * e4.z + k4.z * vv; p += q4.z * S[i0+2];
      S[i0+3] = S[i0+3] * e4.w + k4.w * vv; p += q4.w * S[i0+3];
    }
    p += __shfl_xor(p, 1);
    p += __shfl_xor(p, 2);
    if (r == 0) O[vBase + (size_t)t * VDT + c] = p;
    __syncthreads();
  }
}

// ---------------- epilogue: Y = RMSNorm(o)*w * silu(g), per (token, head) ----------------
__global__ __launch_bounds__(256)
void epilogue(const float* __restrict__ O, const float* __restrict__ G,
              const float* __restrict__ w, float* __restrict__ Y)
{
  const int row = blockIdx.x;
  const int tid = threadIdx.x;
  __shared__ float sred[4];
  for (int h = 0; h < NHEADS; ++h) {
    const size_t base = (size_t)row * VDT + h * DVH;
    const float2 o2 = *(const float2*)&O[base + tid * 2];
    float ss = o2.x * o2.x + o2.y * o2.y;
    #pragma unroll
    for (int off = 32; off > 0; off >>= 1) ss += __shfl_down(ss, off);
    if ((tid & 63) == 0) sred[tid >> 6] = ss;
    __syncthreads();
    const float tot = sred[0] + sred[1] + sred[2] + sred[3];
    const float rs = rsqrtf(tot * (1.f / DVH) + 1e-5f);
    const float2 g2 = *(const float2*)&G[base + tid * 2];
    const float2 w2 = *(const float2*)&w[tid * 2];
    const float y0 = o2.x * rs * w2.x * g2.x / (1.f + expf(-g2.x));
    const float y1 = o2.y * rs * w2.y * g2.y / (1.f + expf(-g2.y));
    *(float2*)&Y[base + tid * 2] = make_float2(y0, y1);
    __syncthreads();
  }
}

extern "C" void kernel_launch(void* const* d_in, const int* in_sizes, int n_in,
                              void* d_out, int out_size, void* d_ws, size_t ws_size,
                              hipStream_t stream)
{
  const float* x    = (const float*)d_in[0];
  const float* Wq   = (const float*)d_in[1];
  const float* Wk   = (const float*)d_in[2];
  const float* Wv   = (const float*)d_in[3];
  const float* Wg   = (const float*)d_in[4];
  const float* gw1  = (const float*)d_in[5];
  const float* gw2  = (const float*)d_in[6];
  const float* gb2  = (const float*)d_in[7];
  const float* gnw  = (const float*)d_in[8];
  const float* Wo   = (const float*)d_in[9];
  float* out = (float*)d_out;

  float* ws = (float*)d_ws;
  float* Qb  = ws;                        // 4M floats
  float* Kbf = ws + (size_t)4*1024*1024;  // 4M
  float* EGK = ws + (size_t)8*1024*1024;  // 4M
  float* Vb  = ws + (size_t)12*1024*1024; // 8M
  float* Gb  = ws + (size_t)20*1024*1024; // 8M
  float* Ob  = ws + (size_t)28*1024*1024; // 8M
  float* Ub  = ws + (size_t)36*1024*1024; // 64K
  float* Y2  = Qb;                        // reuse Q+K region after scan

  const float qscale = 0.0625f;           // DK^-0.5

  gemm_f32<<<dim3(16, 64), 256, 0, stream>>>(x, Wq, Qb,  NTOK, 1024, 1024, qscale);
  gemm_f32<<<dim3(16, 64), 256, 0, stream>>>(x, Wk, Kbf, NTOK, 1024, 1024, 1.f);
  gemm_f32<<<dim3(32, 64), 256, 0, stream>>>(x, Wv, Vb,  NTOK, 2048, 1024, 1.f);
  gemm_f32<<<dim3(32, 64), 256, 0, stream>>>(x, Wg, Gb,  NTOK, 2048, 1024, 1.f);
  gemm_u  <<<64, 256, 0, stream>>>(x, gw1, Ub);
  gate_kernel<<<NTOK, 256, 0, stream>>>(Ub, gw2, gb2, EGK);
  gla_scan<<<dim3(8, 8), 256, 0, stream>>>(Qb, Kbf, EGK, Vb, Ob);
  epilogue<<<NTOK, 256, 0, stream>>>(Ob, Gb, gnw, Y2);
  gemm_f32<<<dim3(16, 64), 256, 0, stream>>>(Y2, Wo, out, NTOK, 1024, 2048, 1.f);
}

// Round 3
// 1422.160 us; speedup vs baseline: 1.9695x; 1.9695x over previous
//
#include <hip/hip_runtime.h>
#include <hip/hip_bf16.h>
#include <math.h>

#define NHEADS 4
#define DKH 256
#define DVH 512
#define SEQL 2048
#define NB 2
#define NTOK (NB*SEQL)     // 4096
#define DM 1024            // d_model
#define KDT 1024           // NHEADS*DKH
#define VDT 2048           // NHEADS*DVH
#define CHUNK 128
#define NCH (SEQL/CHUNK)   // 16

// ---------------- generic fp32 GEMM: C = scale*(A[M,K] @ B[K,N]) ----------------
__global__ __launch_bounds__(256)
void gemm_f32(const float* __restrict__ A, const float* __restrict__ B,
              float* __restrict__ C, int M, int N, int K, float scale)
{
  __shared__ __align__(16) float As[16][68];
  __shared__ __align__(16) float Bs[16][68];
  const int tid = threadIdx.x;
  const int tx = tid & 15, ty = tid >> 4;
  const int bm = blockIdx.y * 64, bn = blockIdx.x * 64;
  float acc[4][4] = {};
  for (int k0 = 0; k0 < K; k0 += 16) {
    {
      const int row = tid >> 2, kk = (tid & 3) << 2;
      const float4 a4 = *(const float4*)&A[(size_t)(bm + row) * K + k0 + kk];
      As[kk+0][row] = a4.x; As[kk+1][row] = a4.y;
      As[kk+2][row] = a4.z; As[kk+3][row] = a4.w;
    }
    {
      const int kk = tid >> 4, n = (tid & 15) << 2;
      *(float4*)&Bs[kk][n] = *(const float4*)&B[(size_t)(k0 + kk) * N + bn + n];
    }
    __syncthreads();
    #pragma unroll
    for (int kk = 0; kk < 16; ++kk) {
      const float4 a4 = *(const float4*)&As[kk][ty << 2];
      const float4 b4 = *(const float4*)&Bs[kk][tx << 2];
      const float av[4] = {a4.x, a4.y, a4.z, a4.w};
      const float bv[4] = {b4.x, b4.y, b4.z, b4.w};
      #pragma unroll
      for (int i = 0; i < 4; ++i)
        #pragma unroll
        for (int j = 0; j < 4; ++j)
          acc[i][j] += av[i] * bv[j];
    }
    __syncthreads();
  }
  #pragma unroll
  for (int i = 0; i < 4; ++i) {
    float4 o4 = make_float4(scale*acc[i][0], scale*acc[i][1], scale*acc[i][2], scale*acc[i][3]);
    *(float4*)&C[(size_t)(bm + (ty << 2) + i) * N + bn + (tx << 2)] = o4;
  }
}

// ---------------- U = x @ gk_w1  (M=4096, N=16, K=1024) ----------------
__global__ __launch_bounds__(256)
void gemm_u(const float* __restrict__ X, const float* __restrict__ W1,
            float* __restrict__ U)
{
  __shared__ float Xs[64][65];
  __shared__ __align__(16) float W1s[64][16];
  const int tid = threadIdx.x;
  const int row0 = blockIdx.x * 64;
  const int rr = tid & 63, gg = tid >> 6;
  float acc[4] = {0.f, 0.f, 0.f, 0.f};
  for (int k0 = 0; k0 < DM; k0 += 64) {
    #pragma unroll
    for (int rep = 0; rep < 4; ++rep) {
      const int m = (tid >> 4) + rep * 16;
      const int kk = (tid & 15) << 2;
      const float4 x4 = *(const float4*)&X[(size_t)(row0 + m) * DM + k0 + kk];
      Xs[kk+0][m] = x4.x; Xs[kk+1][m] = x4.y; Xs[kk+2][m] = x4.z; Xs[kk+3][m] = x4.w;
    }
    {
      const int kk = tid >> 2, n = (tid & 3) << 2;
      *(float4*)&W1s[kk][n] = *(const float4*)&W1[(size_t)(k0 + kk) * 16 + n];
    }
    __syncthreads();
    #pragma unroll
    for (int k2 = 0; k2 < 64; ++k2) {
      const float xv = Xs[k2][rr];
      const float4 w4 = *(const float4*)&W1s[k2][gg << 2];
      acc[0] += xv * w4.x; acc[1] += xv * w4.y; acc[2] += xv * w4.z; acc[3] += xv * w4.w;
    }
    __syncthreads();
  }
  *(float4*)&U[(size_t)(row0 + rr) * 16 + (gg << 2)] =
      make_float4(acc[0], acc[1], acc[2], acc[3]);
}

// ---------------- EG = exp(log_sigmoid(U @ gk_w2 + b2) / 16) (per-step decay) ----
__device__ inline float ls_exp(float z) {
  const float ls = (z >= 0.f) ? -log1pf(expf(-z)) : (z - log1pf(expf(z)));
  return expf(ls * 0.0625f);
}

__global__ __launch_bounds__(256)
void gate_kernel(const float* __restrict__ U, const float* __restrict__ W2,
                 const float* __restrict__ b2, float* __restrict__ EGKo)
{
  __shared__ float Us[16];
  const int row = blockIdx.x, tid = threadIdx.x;
  if (tid < 16) Us[tid] = U[row * 16 + tid];
  __syncthreads();
  const int d0 = tid << 2;
  float4 z = *(const float4*)&b2[d0];
  #pragma unroll
  for (int r = 0; r < 16; ++r) {
    const float u = Us[r];
    const float4 w4 = *(const float4*)&W2[r * 1024 + d0];
    z.x += u * w4.x; z.y += u * w4.y; z.z += u * w4.z; z.w += u * w4.w;
  }
  float4 e = make_float4(ls_exp(z.x), ls_exp(z.y), ls_exp(z.z), ls_exp(z.w));
  *(float4*)&EGKo[(size_t)row * 1024 + d0] = e;
}

// ---------------- chunk_prep: Q->q*Lam, K->k/Lam, EG->kt*LamC, lamC out ----------
__global__ __launch_bounds__(256)
void chunk_prep(float* __restrict__ Q, float* __restrict__ K,
                float* __restrict__ EG, float* __restrict__ lamC)
{
  const int j = blockIdx.x;   // chunk
  const int bh = blockIdx.y;
  const int b = bh >> 2, h = bh & 3;
  const int tid = threadIdx.x;  // dk lane
  const size_t base = ((size_t)(b * SEQL + j * CHUNK)) * KDT + h * DKH + tid;
  float cum = 1.f;
  for (int t = 0; t < CHUNK; t += 4) {
    const size_t i0 = base + (size_t)t * KDT;
    float d[4], q[4], k[4];
    #pragma unroll
    for (int u = 0; u < 4; ++u) {
      d[u] = EG[i0 + (size_t)u * KDT];
      q[u] = Q [i0 + (size_t)u * KDT];
      k[u] = K [i0 + (size_t)u * KDT];
    }
    #pragma unroll
    for (int u = 0; u < 4; ++u) {
      cum *= d[u];
      Q[i0 + (size_t)u * KDT] = q[u] * cum;
      K[i0 + (size_t)u * KDT] = k[u] / cum;
    }
  }
  lamC[(bh * NCH + j) * 256 + tid] = cum;
  for (int t = 0; t < CHUNK; t += 4) {
    const size_t i0 = base + (size_t)t * KDT;
    float k[4];
    #pragma unroll
    for (int u = 0; u < 4; ++u) k[u] = K[i0 + (size_t)u * KDT];
    #pragma unroll
    for (int u = 0; u < 4; ++u) EG[i0 + (size_t)u * KDT] = k[u] * cum;
  }
}

// ---------------- gla_intra: O = tril(qt@kt^T) @ V  (per bh,chunk,dv-half) ------
__global__ __launch_bounds__(256, 1)
void gla_intra(const float* __restrict__ qt, const float* __restrict__ kt,
               const float* __restrict__ V, float* __restrict__ O)
{
  const int half = blockIdx.x;   // dv half (256 cols)
  const int j    = blockIdx.y;   // chunk
  const int bh   = blockIdx.z;
  const int b = bh >> 2, h = bh & 3;
  const int tid = threadIdx.x;
  const int ty = tid >> 4, tx = tid & 15;
  __shared__ float A_s[128 * 133];
  __shared__ __align__(16) float stg[8448];
  float* qtS = stg;          // [32][132] as [k][m]
  float* ktS = stg + 4224;

  const int tok0 = b * SEQL + j * CHUNK;
  const size_t qkBase = (size_t)tok0 * KDT + h * DKH;

  float acc[8][8];
  #pragma unroll
  for (int i = 0; i < 8; ++i)
    #pragma unroll
    for (int jj = 0; jj < 8; ++jj) acc[i][jj] = 0.f;

  const int sm = tid >> 1, skk = (tid & 1) * 16;
  for (int dk0 = 0; dk0 < DKH; dk0 += 32) {
    const float4* qg = (const float4*)&qt[qkBase + (size_t)sm * KDT + dk0 + skk];
    const float4* kg = (const float4*)&kt[qkBase + (size_t)sm * KDT + dk0 + skk];
    float4 q4[4], k4[4];
    #pragma unroll
    for (int i = 0; i < 4; ++i) { q4[i] = qg[i]; k4[i] = kg[i]; }
    #pragma unroll
    for (int i = 0; i < 4; ++i) {
      qtS[(skk + 4*i + 0)*132 + sm] = q4[i].x;
      qtS[(skk + 4*i + 1)*132 + sm] = q4[i].y;
      qtS[(skk + 4*i + 2)*132 + sm] = q4[i].z;
      qtS[(skk + 4*i + 3)*132 + sm] = q4[i].w;
      ktS[(skk + 4*i + 0)*132 + sm] = k4[i].x;
      ktS[(skk + 4*i + 1)*132 + sm] = k4[i].y;
      ktS[(skk + 4*i + 2)*132 + sm] = k4[i].z;
      ktS[(skk + 4*i + 3)*132 + sm] = k4[i].w;
    }
    __syncthreads();
    #pragma unroll
    for (int kk = 0; kk < 32; ++kk) {
      const float4 qa = *(const float4*)&qtS[kk*132 + ty*8];
      const float4 qb = *(const float4*)&qtS[kk*132 + ty*8 + 4];
      const float4 ka = *(const float4*)&ktS[kk*132 + tx*8];
      const float4 kb = *(const float4*)&ktS[kk*132 + tx*8 + 4];
      const float qv[8] = {qa.x,qa.y,qa.z,qa.w,qb.x,qb.y,qb.z,qb.w};
      const float kv[8] = {ka.x,ka.y,ka.z,ka.w,kb.x,kb.y,kb.z,kb.w};
      #pragma unroll
      for (int i = 0; i < 8; ++i)
        #pragma unroll
        for (int jj = 0; jj < 8; ++jj)
          acc[i][jj] += qv[i] * kv[jj];
    }
    __syncthreads();
  }
  #pragma unroll
  for (int i = 0; i < 8; ++i) {
    const int t = ty*8 + i;
    #pragma unroll
    for (int jj = 0; jj < 8; ++jj) {
      const int s = tx*8 + jj;
      A_s[t*133 + s] = (s <= t) ? acc[i][jj] : 0.f;
    }
  }
  __syncthreads();

  float oa[8][16];
  #pragma unroll
  for (int i = 0; i < 8; ++i)
    #pragma unroll
    for (int c = 0; c < 16; ++c) oa[i][c] = 0.f;

  const size_t vBase = (size_t)tok0 * VDT + h * DVH + half * 256;
  const int vss = tid >> 3, vc0 = (tid & 7) * 32;
  for (int s0 = 0; s0 < CHUNK; s0 += 32) {
    const float4* vg = (const float4*)&V[vBase + (size_t)(s0 + vss) * VDT + vc0];
    float4 vv[8];
    #pragma unroll
    for (int i = 0; i < 8; ++i) vv[i] = vg[i];
    #pragma unroll
    for (int i = 0; i < 8; ++i) *(float4*)&stg[vss*260 + vc0 + i*4] = vv[i];
    __syncthreads();
    #pragma unroll
    for (int ss = 0; ss < 32; ++ss) {
      float a[8];
      #pragma unroll
      for (int i = 0; i < 8; ++i) a[i] = A_s[(ty*8 + i)*133 + s0 + ss];
      float4 v4[4];
      #pragma unroll
      for (int c = 0; c < 4; ++c) v4[c] = *(const float4*)&stg[ss*260 + tx*16 + c*4];
      const float vf[16] = {v4[0].x,v4[0].y,v4[0].z,v4[0].w, v4[1].x,v4[1].y,v4[1].z,v4[1].w,
                            v4[2].x,v4[2].y,v4[2].z,v4[2].w, v4[3].x,v4[3].y,v4[3].z,v4[3].w};
      #pragma unroll
      for (int i = 0; i < 8; ++i)
        #pragma unroll
        for (int c = 0; c < 16; ++c)
          oa[i][c] += a[i] * vf[c];
    }
    __syncthreads();
  }
  #pragma unroll
  for (int i = 0; i < 8; ++i) {
    const size_t rb = (size_t)(tok0 + ty*8 + i) * VDT + h * DVH + half * 256 + tx*16;
    #pragma unroll
    for (int c4 = 0; c4 < 4; ++c4)
      *(float4*)&O[rb + c4*4] = make_float4(oa[i][c4*4], oa[i][c4*4+1], oa[i][c4*4+2], oa[i][c4*4+3]);
  }
}

// ---------------- gla_state: sequential over chunks, store chunk-start S_j ------
// grid (32 dv-slices of 16, 8 bh); thread = dk lane; S[dk][16 cols] in regs
__global__ __launch_bounds__(256)
void gla_state(const float* __restrict__ kh, const float* __restrict__ V,
               const float* __restrict__ lamC, float* __restrict__ Sj)
{
  const int sl = blockIdx.x;
  const int bh = blockIdx.y;
  const int b = bh >> 2, h = bh & 3;
  const int tid = threadIdx.x;   // dk
  __shared__ __align__(16) float Vs[128 * 16];
  float S[16];
  #pragma unroll
  for (int i = 0; i < 16; ++i) S[i] = 0.f;
  const int vt = tid >> 1, vc = (tid & 1) * 8;
  for (int j = 0; j < NCH; ++j) {
    const int tok0 = b * SEQL + j * CHUNK;
    const size_t sb = (((size_t)(bh * NCH + j) * 256) + tid) * 512 + sl * 16;
    #pragma unroll
    for (int c4 = 0; c4 < 4; ++c4)
      *(float4*)&Sj[sb + c4*4] = make_float4(S[c4*4], S[c4*4+1], S[c4*4+2], S[c4*4+3]);
    {
      const float4* vg = (const float4*)&V[(size_t)(tok0 + vt) * VDT + h * DVH + sl*16 + vc];
      float4 x0 = vg[0], x1 = vg[1];
      *(float4*)&Vs[vt*16 + vc]     = x0;
      *(float4*)&Vs[vt*16 + vc + 4] = x1;
    }
    __syncthreads();
    const float lam = lamC[(bh * NCH + j) * 256 + tid];
    #pragma unroll
    for (int i = 0; i < 16; ++i) S[i] *= lam;
    const size_t khBase = (size_t)tok0 * KDT + h * DKH + tid;
    for (int t = 0; t < CHUNK; t += 4) {
      float kv[4];
      #pragma unroll
      for (int u = 0; u < 4; ++u) kv[u] = kh[khBase + (size_t)(t + u) * KDT];
      #pragma unroll
      for (int u = 0; u < 4; ++u) {
        const float4 va = *(const float4*)&Vs[(t+u)*16];
        const float4 vb = *(const float4*)&Vs[(t+u)*16 + 4];
        const float4 vc4 = *(const float4*)&Vs[(t+u)*16 + 8];
        const float4 vd = *(const float4*)&Vs[(t+u)*16 + 12];
        S[0]  += kv[u]*va.x;  S[1]  += kv[u]*va.y;  S[2]  += kv[u]*va.z;  S[3]  += kv[u]*va.w;
        S[4]  += kv[u]*vb.x;  S[5]  += kv[u]*vb.y;  S[6]  += kv[u]*vb.z;  S[7]  += kv[u]*vb.w;
        S[8]  += kv[u]*vc4.x; S[9]  += kv[u]*vc4.y; S[10] += kv[u]*vc4.z; S[11] += kv[u]*vc4.w;
        S[12] += kv[u]*vd.x;  S[13] += kv[u]*vd.y;  S[14] += kv[u]*vd.z;  S[15] += kv[u]*vd.w;
      }
    }
    __syncthreads();
  }
}

// ---------------- gla_inter: O += qt @ S_j  (per bh,chunk,dv-quarter) -----------
__global__ __launch_bounds__(256, 2)
void gla_inter(const float* __restrict__ qt, const float* __restrict__ Sj,
               float* __restrict__ O)
{
  const int dq = blockIdx.x;   // 0..3 (128-col quarter)
  const int j  = blockIdx.y;
  const int bh = blockIdx.z;
  const int b = bh >> 2, h = bh & 3;
  const int tid = threadIdx.x;
  const int ty = tid >> 4, tx = tid & 15;
  __shared__ __align__(16) float qtS[4224];   // [32][132] as [k][m]
  __shared__ __align__(16) float SjS[4224];   // [32][132] as [k][c]
  const int tok0 = b * SEQL + j * CHUNK;
  const size_t qkBase = (size_t)tok0 * KDT + h * DKH;
  const size_t sjBase = ((size_t)(bh * NCH + j) * 256) * 512 + dq * 128;
  float acc[8][8];
  #pragma unroll
  for (int i = 0; i < 8; ++i)
    #pragma unroll
    for (int jj = 0; jj < 8; ++jj) acc[i][jj] = 0.f;
  const int sm = tid >> 1, skk = (tid & 1) * 16;
  const int zk = tid >> 3, zc = (tid & 7) * 16;
  for (int dk0 = 0; dk0 < DKH; dk0 += 32) {
    const float4* qg = (const float4*)&qt[qkBase + (size_t)sm * KDT + dk0 + skk];
    float4 q4[4];
    #pragma unroll
    for (int i = 0; i < 4; ++i) q4[i] = qg[i];
    #pragma unroll
    for (int i = 0; i < 4; ++i) {
      qtS[(skk + 4*i + 0)*132 + sm] = q4[i].x;
      qtS[(skk + 4*i + 1)*132 + sm] = q4[i].y;
      qtS[(skk + 4*i + 2)*132 + sm] = q4[i].z;
      qtS[(skk + 4*i + 3)*132 + sm] = q4[i].w;
    }
    {
      const float4* sg = (const float4*)&Sj[sjBase + (size_t)(dk0 + zk) * 512 + zc];
      float4 s4[4];
      #pragma unroll
      for (int i = 0; i < 4; ++i) s4[i] = sg[i];
      #pragma unroll
      for (int i = 0; i < 4; ++i) *(float4*)&SjS[zk*132 + zc + i*4] = s4[i];
    }
    __syncthreads();
    #pragma unroll
    for (int kk = 0; kk < 32; ++kk) {
      const float4 qa = *(const float4*)&qtS[kk*132 + ty*8];
      const float4 qb = *(const float4*)&qtS[kk*132 + ty*8 + 4];
      const float4 sa = *(const float4*)&SjS[kk*132 + tx*8];
      const float4 sb = *(const float4*)&SjS[kk*132 + tx*8 + 4];
      const float qv[8] = {qa.x,qa.y,qa.z,qa.w,qb.x,qb.y,qb.z,qb.w};
      const float sv[8] = {sa.x,sa.y,sa.z,sa.w,sb.x,sb.y,sb.z,sb.w};
      #pragma unroll
      for (int i = 0; i < 8; ++i)
        #pragma unroll
        for (int jj = 0; jj < 8; ++jj)
          acc[i][jj] += qv[i] * sv[jj];
    }
    __syncthreads();
  }
  #pragma unroll
  for (int i = 0; i < 8; ++i) {
    const size_t rb = (size_t)(tok0 + ty*8 + i) * VDT + h * DVH + dq*128 + tx*8;
    float4 o0 = *(const float4*)&O[rb];
    float4 o1 = *(const float4*)&O[rb + 4];
    o0.x += acc[i][0]; o0.y += acc[i][1]; o0.z += acc[i][2]; o0.w += acc[i][3];
    o1.x += acc[i][4]; o1.y += acc[i][5]; o1.z += acc[i][6]; o1.w += acc[i][7];
    *(float4*)&O[rb]     = o0;
    *(float4*)&O[rb + 4] = o1;
  }
}

// ---------------- epilogue: Y = RMSNorm(o)*w * silu(g) ----------------
__global__ __launch_bounds__(256)
void epilogue(const float* __restrict__ O, const float* __restrict__ G,
              const float* __restrict__ w, float* __restrict__ Y)
{
  const int row = blockIdx.x;
  const int tid = threadIdx.x;
  __shared__ float sred[4];
  for (int h = 0; h < NHEADS; ++h) {
    const size_t base = (size_t)row * VDT + h * DVH;
    const float2 o2 = *(const float2*)&O[base + tid * 2];
    float ss = o2.x * o2.x + o2.y * o2.y;
    #pragma unroll
    for (int off = 32; off > 0; off >>= 1) ss += __shfl_down(ss, off);
    if ((tid & 63) == 0) sred[tid >> 6] = ss;
    __syncthreads();
    const float tot = sred[0] + sred[1] + sred[2] + sred[3];
    const float rs = rsqrtf(tot * (1.f / DVH) + 1e-5f);
    const float2 g2 = *(const float2*)&G[base + tid * 2];
    const float2 w2 = *(const float2*)&w[tid * 2];
    const float y0 = o2.x * rs * w2.x * g2.x / (1.f + expf(-g2.x));
    const float y1 = o2.y * rs * w2.y * g2.y / (1.f + expf(-g2.y));
    *(float2*)&Y[base + tid * 2] = make_float2(y0, y1);
    __syncthreads();
  }
}

extern "C" void kernel_launch(void* const* d_in, const int* in_sizes, int n_in,
                              void* d_out, int out_size, void* d_ws, size_t ws_size,
                              hipStream_t stream)
{
  const float* x    = (const float*)d_in[0];
  const float* Wq   = (const float*)d_in[1];
  const float* Wk   = (const float*)d_in[2];
  const float* Wv   = (const float*)d_in[3];
  const float* Wg   = (const float*)d_in[4];
  const float* gw1  = (const float*)d_in[5];
  const float* gw2  = (const float*)d_in[6];
  const float* gb2  = (const float*)d_in[7];
  const float* gnw  = (const float*)d_in[8];
  const float* Wo   = (const float*)d_in[9];
  float* out = (float*)d_out;

  float* ws = (float*)d_ws;
  const size_t M = 1024ull * 1024ull;
  float* Qb   = ws;               // 4M floats (becomes qt, later reused as Y2)
  float* Kbf  = ws + 4*M;         // 4M (becomes kt)
  float* EGK  = ws + 8*M;         // 4M (becomes kh)
  float* Vb   = ws + 12*M;        // 8M
  float* Gb   = ws + 20*M;        // 8M
  float* Ob   = ws + 28*M;        // 8M
  float* Sjb  = ws + 36*M;        // 16M  (chunk-start states)
  float* lamC = ws + 52*M;        // 32K
  float* Ub   = ws + 52*M + 32768; // 64K
  float* Y2   = Qb;

  const float qscale = 0.0625f;   // DK^-0.5

  gemm_f32<<<dim3(16, 64), 256, 0, stream>>>(x, Wq, Qb,  NTOK, 1024, 1024, qscale);
  gemm_f32<<<dim3(16, 64), 256, 0, stream>>>(x, Wk, Kbf, NTOK, 1024, 1024, 1.f);
  gemm_f32<<<dim3(32, 64), 256, 0, stream>>>(x, Wv, Vb,  NTOK, 2048, 1024, 1.f);
  gemm_f32<<<dim3(32, 64), 256, 0, stream>>>(x, Wg, Gb,  NTOK, 2048, 1024, 1.f);
  gemm_u  <<<64, 256, 0, stream>>>(x, gw1, Ub);
  gate_kernel<<<NTOK, 256, 0, stream>>>(Ub, gw2, gb2, EGK);

  chunk_prep<<<dim3(NCH, 8), 256, 0, stream>>>(Qb, Kbf, EGK, lamC);
  gla_intra <<<dim3(2, NCH, 8), 256, 0, stream>>>(Qb, Kbf, Vb, Ob);
  gla_state <<<dim3(32, 8), 256, 0, stream>>>(EGK, Vb, lamC, Sjb);
  gla_inter <<<dim3(4, NCH, 8), 256, 0, stream>>>(Qb, Sjb, Ob);

  epilogue<<<NTOK, 256, 0, stream>>>(Ob, Gb, gnw, Y2);
  gemm_f32<<<dim3(16, 64), 256, 0, stream>>>(Y2, Wo, out, NTOK, 1024, 2048, 1.f);
}

// Round 4
// 646.344 us; speedup vs baseline: 4.3335x; 2.2003x over previous
//
#include <hip/hip_runtime.h>
#include <hip/hip_bf16.h>
#include <math.h>

#define NHEADS 4
#define DKH 256
#define DVH 512
#define SEQL 2048
#define NB 2
#define NTOK (NB*SEQL)     // 4096
#define DM 1024            // d_model
#define KDT 1024           // NHEADS*DKH
#define VDT 2048           // NHEADS*DVH
#define CHUNK 128
#define NCH (SEQL/CHUNK)   // 16

typedef unsigned short u16;
typedef unsigned int   u32;
typedef __attribute__((ext_vector_type(8))) short bf16x8;
typedef __attribute__((ext_vector_type(4))) float f32x4;

__device__ inline u16 f2bf(float f) {
  __hip_bfloat16 h = __float2bfloat16(f);
  return *reinterpret_cast<u16*>(&h);
}

// ---------------- fp32 -> bf16 elementwise (x, 8 elems/thread) ----------------
__global__ __launch_bounds__(256)
void f2bf_kernel(const float* __restrict__ in, u16* __restrict__ out, int n)
{
  const int i = (blockIdx.x * 256 + threadIdx.x) * 8;
  if (i >= n) return;
  const float4 x0 = *(const float4*)&in[i];
  const float4 x1 = *(const float4*)&in[i + 4];
  int4 p;
  p.x = f2bf(x0.x) | ((u32)f2bf(x0.y) << 16);
  p.y = f2bf(x0.z) | ((u32)f2bf(x0.w) << 16);
  p.z = f2bf(x1.x) | ((u32)f2bf(x1.y) << 16);
  p.w = f2bf(x1.z) | ((u32)f2bf(x1.w) << 16);
  *(int4*)&out[i] = p;
}

// ---------------- W[K][N] fp32 -> Wt[N][K] bf16 (64x64 LDS tiles) ---------------
__global__ __launch_bounds__(256)
void transpose_f2bf(const float* __restrict__ W, u16* __restrict__ Wt, int K, int N)
{
  __shared__ float Ts[64][69];   // [n][k]
  const int n0 = blockIdx.x * 64, k0 = blockIdx.y * 64;
  const int tx = threadIdx.x & 15, ty = threadIdx.x >> 4;
  #pragma unroll
  for (int r = 0; r < 4; ++r) {
    const int k = ty + r * 16;
    const float4 w4 = *(const float4*)&W[(size_t)(k0 + k) * N + n0 + tx * 4];
    Ts[tx*4 + 0][k] = w4.x;
    Ts[tx*4 + 1][k] = w4.y;
    Ts[tx*4 + 2][k] = w4.z;
    Ts[tx*4 + 3][k] = w4.w;
  }
  __syncthreads();
  #pragma unroll
  for (int r = 0; r < 4; ++r) {
    const int n = ty + r * 16;
    const u16 u0 = f2bf(Ts[n][tx*4 + 0]);
    const u16 u1 = f2bf(Ts[n][tx*4 + 1]);
    const u16 u2 = f2bf(Ts[n][tx*4 + 2]);
    const u16 u3 = f2bf(Ts[n][tx*4 + 3]);
    unsigned long long pk = (unsigned long long)u0 | ((unsigned long long)u1 << 16)
                          | ((unsigned long long)u2 << 32) | ((unsigned long long)u3 << 48);
    *(unsigned long long*)&Wt[(size_t)(n0 + n) * K + k0 + tx * 4] = pk;
  }
}

// ---------------- bf16 MFMA GEMM: C[M][N] = scale*(A[M][K] @ Bt[N][K]^T) --------
// 128x128 tile, 4 waves (2x2 of 64x64), 16x16x32 MFMA, BK=32, reg-staged LDS.
__global__ __launch_bounds__(256)
void gemm_bf16(const u16* __restrict__ A, const u16* __restrict__ Bt,
               float* __restrict__ C, int M, int N, int K, float scale)
{
  __shared__ __align__(16) u16 As[128 * 32];  // [m][k] 8KB
  __shared__ __align__(16) u16 Bs[128 * 32];  // [n][k] 8KB
  const int tid = threadIdx.x;
  const int lane = tid & 63, wave = tid >> 6;
  const int wr = wave >> 1, wc = wave & 1;
  const int l15 = lane & 15, l4 = lane >> 4;
  const int bm = blockIdx.y * 128, bn = blockIdx.x * 128;

  f32x4 acc[4][4];
  #pragma unroll
  for (int i = 0; i < 4; ++i)
    #pragma unroll
    for (int j = 0; j < 4; ++j)
      acc[i][j] = (f32x4){0.f, 0.f, 0.f, 0.f};

  const int srow = tid >> 2;            // 0..63
  const int scol = (tid & 3) * 8;       // element col (8 bf16 = 16B)
  const u16* Ag = &A [(size_t)(bm + srow) * K + scol];
  const u16* Bg = &Bt[(size_t)(bn + srow) * K + scol];

  // prefetch tile 0
  int4 a0 = *(const int4*)(Ag);
  int4 a1 = *(const int4*)(Ag + (size_t)64 * K);
  int4 b0 = *(const int4*)(Bg);
  int4 b1 = *(const int4*)(Bg + (size_t)64 * K);

  for (int k0 = 0; k0 < K; k0 += 32) {
    __syncthreads();   // previous tile's compute done -> safe to overwrite LDS
    *(int4*)&As[(srow)      * 32 + scol] = a0;
    *(int4*)&As[(64 + srow) * 32 + scol] = a1;
    *(int4*)&Bs[(srow)      * 32 + scol] = b0;
    *(int4*)&Bs[(64 + srow) * 32 + scol] = b1;
    __syncthreads();
    if (k0 + 32 < K) {   // issue next-tile loads早 so latency hides under MFMA
      a0 = *(const int4*)(Ag + k0 + 32);
      a1 = *(const int4*)(Ag + (size_t)64 * K + k0 + 32);
      b0 = *(const int4*)(Bg + k0 + 32);
      b1 = *(const int4*)(Bg + (size_t)64 * K + k0 + 32);
    }
    bf16x8 af[4], bf[4];
    #pragma unroll
    for (int mi = 0; mi < 4; ++mi)
      af[mi] = *(const bf16x8*)&As[(wr*64 + mi*16 + l15) * 32 + l4*8];
    #pragma unroll
    for (int ni = 0; ni < 4; ++ni)
      bf[ni] = *(const bf16x8*)&Bs[(wc*64 + ni*16 + l15) * 32 + l4*8];
    #pragma unroll
    for (int mi = 0; mi < 4; ++mi)
      #pragma unroll
      for (int ni = 0; ni < 4; ++ni)
        acc[mi][ni] = __builtin_amdgcn_mfma_f32_16x16x32_bf16(af[mi], bf[ni], acc[mi][ni], 0, 0, 0);
  }

  // C/D layout: col = lane&15, row = (lane>>4)*4 + reg   [m89/m91 verified]
  #pragma unroll
  for (int mi = 0; mi < 4; ++mi)
    #pragma unroll
    for (int ni = 0; ni < 4; ++ni) {
      const int col = bn + wc*64 + ni*16 + l15;
      #pragma unroll
      for (int r = 0; r < 4; ++r) {
        const int row = bm + wr*64 + mi*16 + l4*4 + r;
        C[(size_t)row * N + col] = acc[mi][ni][r] * scale;
      }
    }
}

// ---------------- U = x @ gk_w1  (M=4096, N=16, K=1024) ----------------
__global__ __launch_bounds__(256)
void gemm_u(const float* __restrict__ X, const float* __restrict__ W1,
            float* __restrict__ U)
{
  __shared__ float Xs[64][65];
  __shared__ __align__(16) float W1s[64][16];
  const int tid = threadIdx.x;
  const int row0 = blockIdx.x * 64;
  const int rr = tid & 63, gg = tid >> 6;
  float acc[4] = {0.f, 0.f, 0.f, 0.f};
  for (int k0 = 0; k0 < DM; k0 += 64) {
    #pragma unroll
    for (int rep = 0; rep < 4; ++rep) {
      const int m = (tid >> 4) + rep * 16;
      const int kk = (tid & 15) << 2;
      const float4 x4 = *(const float4*)&X[(size_t)(row0 + m) * DM + k0 + kk];
      Xs[kk+0][m] = x4.x; Xs[kk+1][m] = x4.y; Xs[kk+2][m] = x4.z; Xs[kk+3][m] = x4.w;
    }
    {
      const int kk = tid >> 2, n = (tid & 3) << 2;
      *(float4*)&W1s[kk][n] = *(const float4*)&W1[(size_t)(k0 + kk) * 16 + n];
    }
    __syncthreads();
    #pragma unroll
    for (int k2 = 0; k2 < 64; ++k2) {
      const float xv = Xs[k2][rr];
      const float4 w4 = *(const float4*)&W1s[k2][gg << 2];
      acc[0] += xv * w4.x; acc[1] += xv * w4.y; acc[2] += xv * w4.z; acc[3] += xv * w4.w;
    }
    __syncthreads();
  }
  *(float4*)&U[(size_t)(row0 + rr) * 16 + (gg << 2)] =
      make_float4(acc[0], acc[1], acc[2], acc[3]);
}

// ---------------- EG = exp(log_sigmoid(U @ gk_w2 + b2) / 16) ----------------
__device__ inline float ls_exp(float z) {
  const float ls = (z >= 0.f) ? -log1pf(expf(-z)) : (z - log1pf(expf(z)));
  return expf(ls * 0.0625f);
}

__global__ __launch_bounds__(256)
void gate_kernel(const float* __restrict__ U, const float* __restrict__ W2,
                 const float* __restrict__ b2, float* __restrict__ EGKo)
{
  __shared__ float Us[16];
  const int row = blockIdx.x, tid = threadIdx.x;
  if (tid < 16) Us[tid] = U[row * 16 + tid];
  __syncthreads();
  const int d0 = tid << 2;
  float4 z = *(const float4*)&b2[d0];
  #pragma unroll
  for (int r = 0; r < 16; ++r) {
    const float u = Us[r];
    const float4 w4 = *(const float4*)&W2[r * 1024 + d0];
    z.x += u * w4.x; z.y += u * w4.y; z.z += u * w4.z; z.w += u * w4.w;
  }
  float4 e = make_float4(ls_exp(z.x), ls_exp(z.y), ls_exp(z.z), ls_exp(z.w));
  *(float4*)&EGKo[(size_t)row * 1024 + d0] = e;
}

// ---------------- chunk_prep: Q->q*Lam, K->k/Lam, EG->kt*LamC, lamC out ----------
__global__ __launch_bounds__(256)
void chunk_prep(float* __restrict__ Q, float* __restrict__ K,
                float* __restrict__ EG, float* __restrict__ lamC)
{
  const int j = blockIdx.x;   // chunk
  const int bh = blockIdx.y;
  const int b = bh >> 2, h = bh & 3;
  const int tid = threadIdx.x;  // dk lane
  const size_t base = ((size_t)(b * SEQL + j * CHUNK)) * KDT + h * DKH + tid;
  float cum = 1.f;
  for (int t = 0; t < CHUNK; t += 4) {
    const size_t i0 = base + (size_t)t * KDT;
    float d[4], q[4], k[4];
    #pragma unroll
    for (int u = 0; u < 4; ++u) {
      d[u] = EG[i0 + (size_t)u * KDT];
      q[u] = Q [i0 + (size_t)u * KDT];
      k[u] = K [i0 + (size_t)u * KDT];
    }
    #pragma unroll
    for (int u = 0; u < 4; ++u) {
      cum *= d[u];
      Q[i0 + (size_t)u * KDT] = q[u] * cum;
      K[i0 + (size_t)u * KDT] = k[u] / cum;
    }
  }
  lamC[(bh * NCH + j) * 256 + tid] = cum;
  for (int t = 0; t < CHUNK; t += 4) {
    const size_t i0 = base + (size_t)t * KDT;
    float k[4];
    #pragma unroll
    for (int u = 0; u < 4; ++u) k[u] = K[i0 + (size_t)u * KDT];
    #pragma unroll
    for (int u = 0; u < 4; ++u) EG[i0 + (size_t)u * KDT] = k[u] * cum;
  }
}

// ---------------- gla_intra: O = tril(qt@kt^T) @ V  (per bh,chunk,dv-half) ------
__global__ __launch_bounds__(256, 1)
void gla_intra(const float* __restrict__ qt, const float* __restrict__ kt,
               const float* __restrict__ V, float* __restrict__ O)
{
  const int half = blockIdx.x;
  const int j    = blockIdx.y;
  const int bh   = blockIdx.z;
  const int b = bh >> 2, h = bh & 3;
  const int tid = threadIdx.x;
  const int ty = tid >> 4, tx = tid & 15;
  __shared__ float A_s[128 * 133];
  __shared__ __align__(16) float stg[8448];
  float* qtS = stg;
  float* ktS = stg + 4224;

  const int tok0 = b * SEQL + j * CHUNK;
  const size_t qkBase = (size_t)tok0 * KDT + h * DKH;

  float acc[8][8];
  #pragma unroll
  for (int i = 0; i < 8; ++i)
    #pragma unroll
    for (int jj = 0; jj < 8; ++jj) acc[i][jj] = 0.f;

  const int sm = tid >> 1, skk = (tid & 1) * 16;
  for (int dk0 = 0; dk0 < DKH; dk0 += 32) {
    const float4* qg = (const float4*)&qt[qkBase + (size_t)sm * KDT + dk0 + skk];
    const float4* kg = (const float4*)&kt[qkBase + (size_t)sm * KDT + dk0 + skk];
    float4 q4[4], k4[4];
    #pragma unroll
    for (int i = 0; i < 4; ++i) { q4[i] = qg[i]; k4[i] = kg[i]; }
    #pragma unroll
    for (int i = 0; i < 4; ++i) {
      qtS[(skk + 4*i + 0)*132 + sm] = q4[i].x;
      qtS[(skk + 4*i + 1)*132 + sm] = q4[i].y;
      qtS[(skk + 4*i + 2)*132 + sm] = q4[i].z;
      qtS[(skk + 4*i + 3)*132 + sm] = q4[i].w;
      ktS[(skk + 4*i + 0)*132 + sm] = k4[i].x;
      ktS[(skk + 4*i + 1)*132 + sm] = k4[i].y;
      ktS[(skk + 4*i + 2)*132 + sm] = k4[i].z;
      ktS[(skk + 4*i + 3)*132 + sm] = k4[i].w;
    }
    __syncthreads();
    #pragma unroll
    for (int kk = 0; kk < 32; ++kk) {
      const float4 qa = *(const float4*)&qtS[kk*132 + ty*8];
      const float4 qb = *(const float4*)&qtS[kk*132 + ty*8 + 4];
      const float4 ka = *(const float4*)&ktS[kk*132 + tx*8];
      const float4 kb = *(const float4*)&ktS[kk*132 + tx*8 + 4];
      const float qv[8] = {qa.x,qa.y,qa.z,qa.w,qb.x,qb.y,qb.z,qb.w};
      const float kv[8] = {ka.x,ka.y,ka.z,ka.w,kb.x,kb.y,kb.z,kb.w};
      #pragma unroll
      for (int i = 0; i < 8; ++i)
        #pragma unroll
        for (int jj = 0; jj < 8; ++jj)
          acc[i][jj] += qv[i] * kv[jj];
    }
    __syncthreads();
  }
  #pragma unroll
  for (int i = 0; i < 8; ++i) {
    const int t = ty*8 + i;
    #pragma unroll
    for (int jj = 0; jj < 8; ++jj) {
      const int s = tx*8 + jj;
      A_s[t*133 + s] = (s <= t) ? acc[i][jj] : 0.f;
    }
  }
  __syncthreads();

  float oa[8][16];
  #pragma unroll
  for (int i = 0; i < 8; ++i)
    #pragma unroll
    for (int c = 0; c < 16; ++c) oa[i][c] = 0.f;

  const size_t vBase = (size_t)tok0 * VDT + h * DVH + half * 256;
  const int vss = tid >> 3, vc0 = (tid & 7) * 32;
  for (int s0 = 0; s0 < CHUNK; s0 += 32) {
    const float4* vg = (const float4*)&V[vBase + (size_t)(s0 + vss) * VDT + vc0];
    float4 vv[8];
    #pragma unroll
    for (int i = 0; i < 8; ++i) vv[i] = vg[i];
    #pragma unroll
    for (int i = 0; i < 8; ++i) *(float4*)&stg[vss*260 + vc0 + i*4] = vv[i];
    __syncthreads();
    #pragma unroll
    for (int ss = 0; ss < 32; ++ss) {
      float a[8];
      #pragma unroll
      for (int i = 0; i < 8; ++i) a[i] = A_s[(ty*8 + i)*133 + s0 + ss];
      float4 v4[4];
      #pragma unroll
      for (int c = 0; c < 4; ++c) v4[c] = *(const float4*)&stg[ss*260 + tx*16 + c*4];
      const float vf[16] = {v4[0].x,v4[0].y,v4[0].z,v4[0].w, v4[1].x,v4[1].y,v4[1].z,v4[1].w,
                            v4[2].x,v4[2].y,v4[2].z,v4[2].w, v4[3].x,v4[3].y,v4[3].z,v4[3].w};
      #pragma unroll
      for (int i = 0; i < 8; ++i)
        #pragma unroll
        for (int c = 0; c < 16; ++c)
          oa[i][c] += a[i] * vf[c];
    }
    __syncthreads();
  }
  #pragma unroll
  for (int i = 0; i < 8; ++i) {
    const size_t rb = (size_t)(tok0 + ty*8 + i) * VDT + h * DVH + half * 256 + tx*16;
    #pragma unroll
    for (int c4 = 0; c4 < 4; ++c4)
      *(float4*)&O[rb + c4*4] = make_float4(oa[i][c4*4], oa[i][c4*4+1], oa[i][c4*4+2], oa[i][c4*4+3]);
  }
}

// ---------------- gla_state: sequential over chunks, store chunk-start S_j ------
__global__ __launch_bounds__(256)
void gla_state(const float* __restrict__ kh, const float* __restrict__ V,
               const float* __restrict__ lamC, float* __restrict__ Sj)
{
  const int sl = blockIdx.x;
  const int bh = blockIdx.y;
  const int b = bh >> 2, h = bh & 3;
  const int tid = threadIdx.x;   // dk
  __shared__ __align__(16) float Vs[128 * 16];
  float S[16];
  #pragma unroll
  for (int i = 0; i < 16; ++i) S[i] = 0.f;
  const int vt = tid >> 1, vc = (tid & 1) * 8;
  for (int j = 0; j < NCH; ++j) {
    const int tok0 = b * SEQL + j * CHUNK;
    const size_t sb = (((size_t)(bh * NCH + j) * 256) + tid) * 512 + sl * 16;
    #pragma unroll
    for (int c4 = 0; c4 < 4; ++c4)
      *(float4*)&Sj[sb + c4*4] = make_float4(S[c4*4], S[c4*4+1], S[c4*4+2], S[c4*4+3]);
    {
      const float4* vg = (const float4*)&V[(size_t)(tok0 + vt) * VDT + h * DVH + sl*16 + vc];
      float4 x0 = vg[0], x1 = vg[1];
      *(float4*)&Vs[vt*16 + vc]     = x0;
      *(float4*)&Vs[vt*16 + vc + 4] = x1;
    }
    __syncthreads();
    const float lam = lamC[(bh * NCH + j) * 256 + tid];
    #pragma unroll
    for (int i = 0; i < 16; ++i) S[i] *= lam;
    const size_t khBase = (size_t)tok0 * KDT + h * DKH + tid;
    for (int t = 0; t < CHUNK; t += 4) {
      float kv[4];
      #pragma unroll
      for (int u = 0; u < 4; ++u) kv[u] = kh[khBase + (size_t)(t + u) * KDT];
      #pragma unroll
      for (int u = 0; u < 4; ++u) {
        const float4 va = *(const float4*)&Vs[(t+u)*16];
        const float4 vb = *(const float4*)&Vs[(t+u)*16 + 4];
        const float4 vc4 = *(const float4*)&Vs[(t+u)*16 + 8];
        const float4 vd = *(const float4*)&Vs[(t+u)*16 + 12];
        S[0]  += kv[u]*va.x;  S[1]  += kv[u]*va.y;  S[2]  += kv[u]*va.z;  S[3]  += kv[u]*va.w;
        S[4]  += kv[u]*vb.x;  S[5]  += kv[u]*vb.y;  S[6]  += kv[u]*vb.z;  S[7]  += kv[u]*vb.w;
        S[8]  += kv[u]*vc4.x; S[9]  += kv[u]*vc4.y; S[10] += kv[u]*vc4.z; S[11] += kv[u]*vc4.w;
        S[12] += kv[u]*vd.x;  S[13] += kv[u]*vd.y;  S[14] += kv[u]*vd.z;  S[15] += kv[u]*vd.w;
      }
    }
    __syncthreads();
  }
}

// ---------------- gla_inter: O += qt @ S_j  (per bh,chunk,dv-quarter) -----------
__global__ __launch_bounds__(256, 2)
void gla_inter(const float* __restrict__ qt, const float* __restrict__ Sj,
               float* __restrict__ O)
{
  const int dq = blockIdx.x;
  const int j  = blockIdx.y;
  const int bh = blockIdx.z;
  const int b = bh >> 2, h = bh & 3;
  const int tid = threadIdx.x;
  const int ty = tid >> 4, tx = tid & 15;
  __shared__ __align__(16) float qtS[4224];
  __shared__ __align__(16) float SjS[4224];
  const int tok0 = b * SEQL + j * CHUNK;
  const size_t qkBase = (size_t)tok0 * KDT + h * DKH;
  const size_t sjBase = ((size_t)(bh * NCH + j) * 256) * 512 + dq * 128;
  float acc[8][8];
  #pragma unroll
  for (int i = 0; i < 8; ++i)
    #pragma unroll
    for (int jj = 0; jj < 8; ++jj) acc[i][jj] = 0.f;
  const int sm = tid >> 1, skk = (tid & 1) * 16;
  const int zk = tid >> 3, zc = (tid & 7) * 16;
  for (int dk0 = 0; dk0 < DKH; dk0 += 32) {
    const float4* qg = (const float4*)&qt[qkBase + (size_t)sm * KDT + dk0 + skk];
    float4 q4[4];
    #pragma unroll
    for (int i = 0; i < 4; ++i) q4[i] = qg[i];
    #pragma unroll
    for (int i = 0; i < 4; ++i) {
      qtS[(skk + 4*i + 0)*132 + sm] = q4[i].x;
      qtS[(skk + 4*i + 1)*132 + sm] = q4[i].y;
      qtS[(skk + 4*i + 2)*132 + sm] = q4[i].z;
      qtS[(skk + 4*i + 3)*132 + sm] = q4[i].w;
    }
    {
      const float4* sg = (const float4*)&Sj[sjBase + (size_t)(dk0 + zk) * 512 + zc];
      float4 s4[4];
      #pragma unroll
      for (int i = 0; i < 4; ++i) s4[i] = sg[i];
      #pragma unroll
      for (int i = 0; i < 4; ++i) *(float4*)&SjS[zk*132 + zc + i*4] = s4[i];
    }
    __syncthreads();
    #pragma unroll
    for (int kk = 0; kk < 32; ++kk) {
      const float4 qa = *(const float4*)&qtS[kk*132 + ty*8];
      const float4 qb = *(const float4*)&qtS[kk*132 + ty*8 + 4];
      const float4 sa = *(const float4*)&SjS[kk*132 + tx*8];
      const float4 sb = *(const float4*)&SjS[kk*132 + tx*8 + 4];
      const float qv[8] = {qa.x,qa.y,qa.z,qa.w,qb.x,qb.y,qb.z,qb.w};
      const float sv[8] = {sa.x,sa.y,sa.z,sa.w,sb.x,sb.y,sb.z,sb.w};
      #pragma unroll
      for (int i = 0; i < 8; ++i)
        #pragma unroll
        for (int jj = 0; jj < 8; ++jj)
          acc[i][jj] += qv[i] * sv[jj];
    }
    __syncthreads();
  }
  #pragma unroll
  for (int i = 0; i < 8; ++i) {
    const size_t rb = (size_t)(tok0 + ty*8 + i) * VDT + h * DVH + dq*128 + tx*8;
    float4 o0 = *(const float4*)&O[rb];
    float4 o1 = *(const float4*)&O[rb + 4];
    o0.x += acc[i][0]; o0.y += acc[i][1]; o0.z += acc[i][2]; o0.w += acc[i][3];
    o1.x += acc[i][4]; o1.y += acc[i][5]; o1.z += acc[i][6]; o1.w += acc[i][7];
    *(float4*)&O[rb]     = o0;
    *(float4*)&O[rb + 4] = o1;
  }
}

// ---------------- epilogue: Y(bf16) = RMSNorm(o)*w * silu(g) ----------------
__global__ __launch_bounds__(256)
void epilogue(const float* __restrict__ O, const float* __restrict__ G,
              const float* __restrict__ w, u16* __restrict__ Y)
{
  const int row = blockIdx.x;
  const int tid = threadIdx.x;
  __shared__ float sred[4];
  for (int h = 0; h < NHEADS; ++h) {
    const size_t base = (size_t)row * VDT + h * DVH;
    const float2 o2 = *(const float2*)&O[base + tid * 2];
    float ss = o2.x * o2.x + o2.y * o2.y;
    #pragma unroll
    for (int off = 32; off > 0; off >>= 1) ss += __shfl_down(ss, off);
    if ((tid & 63) == 0) sred[tid >> 6] = ss;
    __syncthreads();
    const float tot = sred[0] + sred[1] + sred[2] + sred[3];
    const float rs = rsqrtf(tot * (1.f / DVH) + 1e-5f);
    const float2 g2 = *(const float2*)&G[base + tid * 2];
    const float2 w2 = *(const float2*)&w[tid * 2];
    const float y0 = o2.x * rs * w2.x * g2.x / (1.f + expf(-g2.x));
    const float y1 = o2.y * rs * w2.y * g2.y / (1.f + expf(-g2.y));
    const u32 pk = (u32)f2bf(y0) | ((u32)f2bf(y1) << 16);
    *(u32*)&Y[base + tid * 2] = pk;
    __syncthreads();
  }
}

extern "C" void kernel_launch(void* const* d_in, const int* in_sizes, int n_in,
                              void* d_out, int out_size, void* d_ws, size_t ws_size,
                              hipStream_t stream)
{
  const float* x    = (const float*)d_in[0];
  const float* Wq   = (const float*)d_in[1];
  const float* Wk   = (const float*)d_in[2];
  const float* Wv   = (const float*)d_in[3];
  const float* Wg   = (const float*)d_in[4];
  const float* gw1  = (const float*)d_in[5];
  const float* gw2  = (const float*)d_in[6];
  const float* gb2  = (const float*)d_in[7];
  const float* gnw  = (const float*)d_in[8];
  const float* Wo   = (const float*)d_in[9];
  float* out = (float*)d_out;

  float* ws = (float*)d_ws;
  const size_t M = 1024ull * 1024ull;
  float* Qb   = ws;               // 4M floats (qt)
  float* Kbf  = ws + 4*M;         // 4M (kt)
  float* EGK  = ws + 8*M;         // 4M (kh)
  float* Vb   = ws + 12*M;        // 8M
  float* Gb   = ws + 20*M;        // 8M
  float* Ob   = ws + 28*M;        // 8M
  float* Sjb  = ws + 36*M;        // 16M
  float* lamC = ws + 52*M;        // 32K floats
  float* Ub   = ws + 52*M + 32768;  // 64K floats
  // bf16 region (float-slot offsets; 2 u16 per slot)
  u16* xb  = (u16*)(ws + 53*M);             // 4M u16 (2M slots)
  u16* Wqb = (u16*)(ws + 55*M);             // 1M u16
  u16* Wkb = (u16*)(ws + 55*M + 512*1024);  // 1M u16
  u16* Wvb = (u16*)(ws + 56*M);             // 2M u16
  u16* Wgb = (u16*)(ws + 57*M);             // 2M u16
  u16* Wob = (u16*)(ws + 58*M);             // 2M u16
  u16* Y2b = (u16*)Qb;                      // 8M u16 = 16MB, reuses qt after gla_inter

  const float qscale = 0.0625f;   // DK^-0.5

  // fp32 -> bf16 conversions (+ weight transposes to [N][K])
  f2bf_kernel  <<<2048, 256, 0, stream>>>(x, xb, NTOK * DM);
  transpose_f2bf<<<dim3(16, 16), 256, 0, stream>>>(Wq, Wqb, 1024, 1024);
  transpose_f2bf<<<dim3(16, 16), 256, 0, stream>>>(Wk, Wkb, 1024, 1024);
  transpose_f2bf<<<dim3(32, 16), 256, 0, stream>>>(Wv, Wvb, 1024, 2048);
  transpose_f2bf<<<dim3(32, 16), 256, 0, stream>>>(Wg, Wgb, 1024, 2048);
  transpose_f2bf<<<dim3(16, 32), 256, 0, stream>>>(Wo, Wob, 2048, 1024);

  // projections (bf16 MFMA, fp32 out)
  gemm_bf16<<<dim3( 8, 32), 256, 0, stream>>>(xb, Wqb, Qb,  NTOK, 1024, 1024, qscale);
  gemm_bf16<<<dim3( 8, 32), 256, 0, stream>>>(xb, Wkb, Kbf, NTOK, 1024, 1024, 1.f);
  gemm_bf16<<<dim3(16, 32), 256, 0, stream>>>(xb, Wvb, Vb,  NTOK, 2048, 1024, 1.f);
  gemm_bf16<<<dim3(16, 32), 256, 0, stream>>>(xb, Wgb, Gb,  NTOK, 2048, 1024, 1.f);
  gemm_u  <<<64, 256, 0, stream>>>(x, gw1, Ub);
  gate_kernel<<<NTOK, 256, 0, stream>>>(Ub, gw2, gb2, EGK);

  // chunked GLA (fp32, unchanged)
  chunk_prep<<<dim3(NCH, 8), 256, 0, stream>>>(Qb, Kbf, EGK, lamC);
  gla_intra <<<dim3(2, NCH, 8), 256, 0, stream>>>(Qb, Kbf, Vb, Ob);
  gla_state <<<dim3(32, 8), 256, 0, stream>>>(EGK, Vb, lamC, Sjb);
  gla_inter <<<dim3(4, NCH, 8), 256, 0, stream>>>(Qb, Sjb, Ob);

  // epilogue -> bf16, then output GEMM (bf16 MFMA)
  epilogue<<<NTOK, 256, 0, stream>>>(Ob, Gb, gnw, Y2b);
  gemm_bf16<<<dim3(8, 32), 256, 0, stream>>>(Y2b, Wob, out, NTOK, 1024, 2048, 1.f);
}

// Round 5
// 479.662 us; speedup vs baseline: 5.8394x; 1.3475x over previous
//
#include <hip/hip_runtime.h>
#include <hip/hip_bf16.h>
#include <math.h>

#define NHEADS 4
#define DKH 256
#define DVH 512
#define SEQL 2048
#define NB 2
#define NTOK (NB*SEQL)     // 4096
#define DM 1024            // d_model
#define KDT 1024           // NHEADS*DKH
#define VDT 2048           // NHEADS*DVH
#define CHUNK 128
#define NCH (SEQL/CHUNK)   // 16

typedef unsigned short u16;
typedef unsigned int   u32;
typedef __attribute__((ext_vector_type(8))) short bf16x8;
typedef __attribute__((ext_vector_type(4))) float f32x4;

__device__ inline u16 f2bf(float f) {
  __hip_bfloat16 h = __float2bfloat16(f);
  return *reinterpret_cast<u16*>(&h);
}

// ---------------- fp32 -> bf16 elementwise (x, 8 elems/thread) ----------------
__global__ __launch_bounds__(256)
void f2bf_kernel(const float* __restrict__ in, u16* __restrict__ out, int n)
{
  const int i = (blockIdx.x * 256 + threadIdx.x) * 8;
  if (i >= n) return;
  const float4 x0 = *(const float4*)&in[i];
  const float4 x1 = *(const float4*)&in[i + 4];
  int4 p;
  p.x = f2bf(x0.x) | ((u32)f2bf(x0.y) << 16);
  p.y = f2bf(x0.z) | ((u32)f2bf(x0.w) << 16);
  p.z = f2bf(x1.x) | ((u32)f2bf(x1.y) << 16);
  p.w = f2bf(x1.z) | ((u32)f2bf(x1.w) << 16);
  *(int4*)&out[i] = p;
}

// ---------------- W[K][N] fp32 -> Wt[N][K] bf16 (64x64 LDS tiles) ---------------
__global__ __launch_bounds__(256)
void transpose_f2bf(const float* __restrict__ W, u16* __restrict__ Wt, int K, int N)
{
  __shared__ float Ts[64][69];   // [n][k]
  const int n0 = blockIdx.x * 64, k0 = blockIdx.y * 64;
  const int tx = threadIdx.x & 15, ty = threadIdx.x >> 4;
  #pragma unroll
  for (int r = 0; r < 4; ++r) {
    const int k = ty + r * 16;
    const float4 w4 = *(const float4*)&W[(size_t)(k0 + k) * N + n0 + tx * 4];
    Ts[tx*4 + 0][k] = w4.x;
    Ts[tx*4 + 1][k] = w4.y;
    Ts[tx*4 + 2][k] = w4.z;
    Ts[tx*4 + 3][k] = w4.w;
  }
  __syncthreads();
  #pragma unroll
  for (int r = 0; r < 4; ++r) {
    const int n = ty + r * 16;
    const u16 u0 = f2bf(Ts[n][tx*4 + 0]);
    const u16 u1 = f2bf(Ts[n][tx*4 + 1]);
    const u16 u2 = f2bf(Ts[n][tx*4 + 2]);
    const u16 u3 = f2bf(Ts[n][tx*4 + 3]);
    unsigned long long pk = (unsigned long long)u0 | ((unsigned long long)u1 << 16)
                          | ((unsigned long long)u2 << 32) | ((unsigned long long)u3 << 48);
    *(unsigned long long*)&Wt[(size_t)(n0 + n) * K + k0 + tx * 4] = pk;
  }
}

// ---------------- bf16 MFMA GEMM: C[M][N] = scale*(A[M][K] @ Bt[N][K]^T) --------
__global__ __launch_bounds__(256)
void gemm_bf16(const u16* __restrict__ A, const u16* __restrict__ Bt,
               float* __restrict__ C, int M, int N, int K, float scale)
{
  __shared__ __align__(16) u16 As[128 * 32];  // [m][k] 8KB
  __shared__ __align__(16) u16 Bs[128 * 32];  // [n][k] 8KB
  const int tid = threadIdx.x;
  const int lane = tid & 63, wave = tid >> 6;
  const int wr = wave >> 1, wc = wave & 1;
  const int l15 = lane & 15, l4 = lane >> 4;
  const int bm = blockIdx.y * 128, bn = blockIdx.x * 128;

  f32x4 acc[4][4];
  #pragma unroll
  for (int i = 0; i < 4; ++i)
    #pragma unroll
    for (int j = 0; j < 4; ++j)
      acc[i][j] = (f32x4){0.f, 0.f, 0.f, 0.f};

  const int srow = tid >> 2;
  const int scol = (tid & 3) * 8;
  const u16* Ag = &A [(size_t)(bm + srow) * K + scol];
  const u16* Bg = &Bt[(size_t)(bn + srow) * K + scol];

  int4 a0 = *(const int4*)(Ag);
  int4 a1 = *(const int4*)(Ag + (size_t)64 * K);
  int4 b0 = *(const int4*)(Bg);
  int4 b1 = *(const int4*)(Bg + (size_t)64 * K);

  for (int k0 = 0; k0 < K; k0 += 32) {
    __syncthreads();
    *(int4*)&As[(srow)      * 32 + scol] = a0;
    *(int4*)&As[(64 + srow) * 32 + scol] = a1;
    *(int4*)&Bs[(srow)      * 32 + scol] = b0;
    *(int4*)&Bs[(64 + srow) * 32 + scol] = b1;
    __syncthreads();
    if (k0 + 32 < K) {   // issue next-tile loads so latency hides under MFMA
      a0 = *(const int4*)(Ag + k0 + 32);
      a1 = *(const int4*)(Ag + (size_t)64 * K + k0 + 32);
      b0 = *(const int4*)(Bg + k0 + 32);
      b1 = *(const int4*)(Bg + (size_t)64 * K + k0 + 32);
    }
    bf16x8 af[4], bfv[4];
    #pragma unroll
    for (int mi = 0; mi < 4; ++mi)
      af[mi] = *(const bf16x8*)&As[(wr*64 + mi*16 + l15) * 32 + l4*8];
    #pragma unroll
    for (int ni = 0; ni < 4; ++ni)
      bfv[ni] = *(const bf16x8*)&Bs[(wc*64 + ni*16 + l15) * 32 + l4*8];
    #pragma unroll
    for (int mi = 0; mi < 4; ++mi)
      #pragma unroll
      for (int ni = 0; ni < 4; ++ni)
        acc[mi][ni] = __builtin_amdgcn_mfma_f32_16x16x32_bf16(af[mi], bfv[ni], acc[mi][ni], 0, 0, 0);
  }

  #pragma unroll
  for (int mi = 0; mi < 4; ++mi)
    #pragma unroll
    for (int ni = 0; ni < 4; ++ni) {
      const int col = bn + wc*64 + ni*16 + l15;
      #pragma unroll
      for (int r = 0; r < 4; ++r) {
        const int row = bm + wr*64 + mi*16 + l4*4 + r;
        C[(size_t)row * N + col] = acc[mi][ni][r] * scale;
      }
    }
}

// ---------------- U = x @ gk_w1  (M=4096, N=16, K=1024) ----------------
__global__ __launch_bounds__(256)
void gemm_u(const float* __restrict__ X, const float* __restrict__ W1,
            float* __restrict__ U)
{
  __shared__ float Xs[64][65];
  __shared__ __align__(16) float W1s[64][16];
  const int tid = threadIdx.x;
  const int row0 = blockIdx.x * 64;
  const int rr = tid & 63, gg = tid >> 6;
  float acc[4] = {0.f, 0.f, 0.f, 0.f};
  for (int k0 = 0; k0 < DM; k0 += 64) {
    #pragma unroll
    for (int rep = 0; rep < 4; ++rep) {
      const int m = (tid >> 4) + rep * 16;
      const int kk = (tid & 15) << 2;
      const float4 x4 = *(const float4*)&X[(size_t)(row0 + m) * DM + k0 + kk];
      Xs[kk+0][m] = x4.x; Xs[kk+1][m] = x4.y; Xs[kk+2][m] = x4.z; Xs[kk+3][m] = x4.w;
    }
    {
      const int kk = tid >> 2, n = (tid & 3) << 2;
      *(float4*)&W1s[kk][n] = *(const float4*)&W1[(size_t)(k0 + kk) * 16 + n];
    }
    __syncthreads();
    #pragma unroll
    for (int k2 = 0; k2 < 64; ++k2) {
      const float xv = Xs[k2][rr];
      const float4 w4 = *(const float4*)&W1s[k2][gg << 2];
      acc[0] += xv * w4.x; acc[1] += xv * w4.y; acc[2] += xv * w4.z; acc[3] += xv * w4.w;
    }
    __syncthreads();
  }
  *(float4*)&U[(size_t)(row0 + rr) * 16 + (gg << 2)] =
      make_float4(acc[0], acc[1], acc[2], acc[3]);
}

// ---------------- EG = exp(log_sigmoid(U @ gk_w2 + b2) / 16) ----------------
__device__ inline float ls_exp(float z) {
  const float ls = (z >= 0.f) ? -log1pf(expf(-z)) : (z - log1pf(expf(z)));
  return expf(ls * 0.0625f);
}

__global__ __launch_bounds__(256)
void gate_kernel(const float* __restrict__ U, const float* __restrict__ W2,
                 const float* __restrict__ b2, float* __restrict__ EGKo)
{
  __shared__ float Us[16];
  const int row = blockIdx.x, tid = threadIdx.x;
  if (tid < 16) Us[tid] = U[row * 16 + tid];
  __syncthreads();
  const int d0 = tid << 2;
  float4 z = *(const float4*)&b2[d0];
  #pragma unroll
  for (int r = 0; r < 16; ++r) {
    const float u = Us[r];
    const float4 w4 = *(const float4*)&W2[r * 1024 + d0];
    z.x += u * w4.x; z.y += u * w4.y; z.z += u * w4.z; z.w += u * w4.w;
  }
  float4 e = make_float4(ls_exp(z.x), ls_exp(z.y), ls_exp(z.z), ls_exp(z.w));
  *(float4*)&EGKo[(size_t)row * 1024 + d0] = e;
}

// ---------------- chunk_prep: Q->q*Lam, K->k/Lam, EG->kt*LamC, lamC out ----------
__global__ __launch_bounds__(256)
void chunk_prep(float* __restrict__ Q, float* __restrict__ K,
                float* __restrict__ EG, float* __restrict__ lamC)
{
  const int j = blockIdx.x;   // chunk
  const int bh = blockIdx.y;
  const int b = bh >> 2, h = bh & 3;
  const int tid = threadIdx.x;  // dk lane
  const size_t base = ((size_t)(b * SEQL + j * CHUNK)) * KDT + h * DKH + tid;
  float cum = 1.f;
  for (int t = 0; t < CHUNK; t += 4) {
    const size_t i0 = base + (size_t)t * KDT;
    float d[4], q[4], k[4];
    #pragma unroll
    for (int u = 0; u < 4; ++u) {
      d[u] = EG[i0 + (size_t)u * KDT];
      q[u] = Q [i0 + (size_t)u * KDT];
      k[u] = K [i0 + (size_t)u * KDT];
    }
    #pragma unroll
    for (int u = 0; u < 4; ++u) {
      cum *= d[u];
      Q[i0 + (size_t)u * KDT] = q[u] * cum;
      K[i0 + (size_t)u * KDT] = k[u] / cum;
    }
  }
  lamC[(bh * NCH + j) * 256 + tid] = cum;
  for (int t = 0; t < CHUNK; t += 4) {
    const size_t i0 = base + (size_t)t * KDT;
    float k[4];
    #pragma unroll
    for (int u = 0; u < 4; ++u) k[u] = K[i0 + (size_t)u * KDT];
    #pragma unroll
    for (int u = 0; u < 4; ++u) EG[i0 + (size_t)u * KDT] = k[u] * cum;
  }
}

// ---------------- gla_intra: O = tril(qt@kt^T) @ V  (per bh,chunk,dv-half) ------
__global__ __launch_bounds__(256, 1)
void gla_intra(const float* __restrict__ qt, const float* __restrict__ kt,
               const float* __restrict__ V, float* __restrict__ O)
{
  const int half = blockIdx.x;
  const int j    = blockIdx.y;
  const int bh   = blockIdx.z;
  const int b = bh >> 2, h = bh & 3;
  const int tid = threadIdx.x;
  const int ty = tid >> 4, tx = tid & 15;
  __shared__ float A_s[128 * 133];
  __shared__ __align__(16) float stg[8448];
  float* qtS = stg;
  float* ktS = stg + 4224;

  const int tok0 = b * SEQL + j * CHUNK;
  const size_t qkBase = (size_t)tok0 * KDT + h * DKH;

  float acc[8][8];
  #pragma unroll
  for (int i = 0; i < 8; ++i)
    #pragma unroll
    for (int jj = 0; jj < 8; ++jj) acc[i][jj] = 0.f;

  const int sm = tid >> 1, skk = (tid & 1) * 16;
  for (int dk0 = 0; dk0 < DKH; dk0 += 32) {
    const float4* qg = (const float4*)&qt[qkBase + (size_t)sm * KDT + dk0 + skk];
    const float4* kg = (const float4*)&kt[qkBase + (size_t)sm * KDT + dk0 + skk];
    float4 q4[4], k4[4];
    #pragma unroll
    for (int i = 0; i < 4; ++i) { q4[i] = qg[i]; k4[i] = kg[i]; }
    #pragma unroll
    for (int i = 0; i < 4; ++i) {
      qtS[(skk + 4*i + 0)*132 + sm] = q4[i].x;
      qtS[(skk + 4*i + 1)*132 + sm] = q4[i].y;
      qtS[(skk + 4*i + 2)*132 + sm] = q4[i].z;
      qtS[(skk + 4*i + 3)*132 + sm] = q4[i].w;
      ktS[(skk + 4*i + 0)*132 + sm] = k4[i].x;
      ktS[(skk + 4*i + 1)*132 + sm] = k4[i].y;
      ktS[(skk + 4*i + 2)*132 + sm] = k4[i].z;
      ktS[(skk + 4*i + 3)*132 + sm] = k4[i].w;
    }
    __syncthreads();
    #pragma unroll
    for (int kk = 0; kk < 32; ++kk) {
      const float4 qa = *(const float4*)&qtS[kk*132 + ty*8];
      const float4 qb = *(const float4*)&qtS[kk*132 + ty*8 + 4];
      const float4 ka = *(const float4*)&ktS[kk*132 + tx*8];
      const float4 kb = *(const float4*)&ktS[kk*132 + tx*8 + 4];
      const float qv[8] = {qa.x,qa.y,qa.z,qa.w,qb.x,qb.y,qb.z,qb.w};
      const float kv[8] = {ka.x,ka.y,ka.z,ka.w,kb.x,kb.y,kb.z,kb.w};
      #pragma unroll
      for (int i = 0; i < 8; ++i)
        #pragma unroll
        for (int jj = 0; jj < 8; ++jj)
          acc[i][jj] += qv[i] * kv[jj];
    }
    __syncthreads();
  }
  #pragma unroll
  for (int i = 0; i < 8; ++i) {
    const int t = ty*8 + i;
    #pragma unroll
    for (int jj = 0; jj < 8; ++jj) {
      const int s = tx*8 + jj;
      A_s[t*133 + s] = (s <= t) ? acc[i][jj] : 0.f;
    }
  }
  __syncthreads();

  float oa[8][16];
  #pragma unroll
  for (int i = 0; i < 8; ++i)
    #pragma unroll
    for (int c = 0; c < 16; ++c) oa[i][c] = 0.f;

  const size_t vBase = (size_t)tok0 * VDT + h * DVH + half * 256;
  const int vss = tid >> 3, vc0 = (tid & 7) * 32;
  for (int s0 = 0; s0 < CHUNK; s0 += 32) {
    const float4* vg = (const float4*)&V[vBase + (size_t)(s0 + vss) * VDT + vc0];
    float4 vv[8];
    #pragma unroll
    for (int i = 0; i < 8; ++i) vv[i] = vg[i];
    #pragma unroll
    for (int i = 0; i < 8; ++i) *(float4*)&stg[vss*260 + vc0 + i*4] = vv[i];
    __syncthreads();
    #pragma unroll
    for (int ss = 0; ss < 32; ++ss) {
      float a[8];
      #pragma unroll
      for (int i = 0; i < 8; ++i) a[i] = A_s[(ty*8 + i)*133 + s0 + ss];
      float4 v4[4];
      #pragma unroll
      for (int c = 0; c < 4; ++c) v4[c] = *(const float4*)&stg[ss*260 + tx*16 + c*4];
      const float vf[16] = {v4[0].x,v4[0].y,v4[0].z,v4[0].w, v4[1].x,v4[1].y,v4[1].z,v4[1].w,
                            v4[2].x,v4[2].y,v4[2].z,v4[2].w, v4[3].x,v4[3].y,v4[3].z,v4[3].w};
      #pragma unroll
      for (int i = 0; i < 8; ++i)
        #pragma unroll
        for (int c = 0; c < 16; ++c)
          oa[i][c] += a[i] * vf[c];
    }
    __syncthreads();
  }
  #pragma unroll
  for (int i = 0; i < 8; ++i) {
    const size_t rb = (size_t)(tok0 + ty*8 + i) * VDT + h * DVH + half * 256 + tx*16;
    #pragma unroll
    for (int c4 = 0; c4 < 4; ++c4)
      *(float4*)&O[rb + c4*4] = make_float4(oa[i][c4*4], oa[i][c4*4+1], oa[i][c4*4+2], oa[i][c4*4+3]);
  }
}

// ---------------- gla_pstate: P_j = kh_j^T @ V_j  (chunk-parallel GEMM) ---------
// kh[t][dk], V[t][dv] are both [K][M]/[K][N] row-major -> no transpose in staging.
// grid: (8 dv-tiles, 4 dk-tiles, 128 bh*chunk); P written into Sjb layout.
__global__ __launch_bounds__(256)
void gla_pstate(const float* __restrict__ kh, const float* __restrict__ V,
                float* __restrict__ P)
{
  __shared__ __align__(16) float As[16][68];   // [k][dk]
  __shared__ __align__(16) float Bs[16][68];   // [k][dv]
  const int tid = threadIdx.x;
  const int tx = tid & 15, ty = tid >> 4;
  const int bn = blockIdx.x * 64;          // dv
  const int bm = blockIdx.y * 64;          // dk
  const int jc = blockIdx.z;               // bh*NCH + j
  const int bh = jc >> 4, j = jc & 15;
  const int b = bh >> 2, h = bh & 3;
  const int tok0 = b * SEQL + j * CHUNK;
  float acc[4][4] = {};
  const int skk = tid >> 4;         // k row 0..15
  const int sc4 = (tid & 15) << 2;  // col
  for (int k0 = 0; k0 < CHUNK; k0 += 16) {
    const size_t t = (size_t)(tok0 + k0 + skk);
    *(float4*)&As[skk][sc4] = *(const float4*)&kh[t * KDT + h * DKH + bm + sc4];
    *(float4*)&Bs[skk][sc4] = *(const float4*)&V [t * VDT + h * DVH + bn + sc4];
    __syncthreads();
    #pragma unroll
    for (int kk = 0; kk < 16; ++kk) {
      const float4 a4 = *(const float4*)&As[kk][ty << 2];
      const float4 b4 = *(const float4*)&Bs[kk][tx << 2];
      const float av[4] = {a4.x, a4.y, a4.z, a4.w};
      const float bv[4] = {b4.x, b4.y, b4.z, b4.w};
      #pragma unroll
      for (int i = 0; i < 4; ++i)
        #pragma unroll
        for (int jj = 0; jj < 4; ++jj)
          acc[i][jj] += av[i] * bv[jj];
    }
    __syncthreads();
  }
  #pragma unroll
  for (int i = 0; i < 4; ++i) {
    float4 o4 = make_float4(acc[i][0], acc[i][1], acc[i][2], acc[i][3]);
    *(float4*)&P[((size_t)jc * 256 + bm + (ty << 2) + i) * 512 + bn + (tx << 2)] = o4;
  }
}

// ---------------- gla_sscan: in-place P_j -> S_j (chunk-start states) -----------
// S_0 = 0; loop j: tmp = P_j; store S; S = lam_j*S + tmp.  grid (128, 8bh).
__global__ __launch_bounds__(256)
void gla_sscan(float* __restrict__ Sj, const float* __restrict__ lamC)
{
  const int bh = blockIdx.y;
  const int e0 = blockIdx.x * 1024 + threadIdx.x * 4;   // elem in 256*512
  const int dk = e0 >> 9;
  const int dv = e0 & 511;
  float4 S = make_float4(0.f, 0.f, 0.f, 0.f);
  for (int j = 0; j < NCH; ++j) {
    const int cidx = (bh * NCH + j) * 256 + dk;
    const size_t idx = (size_t)cidx * 512 + dv;
    const float4 tmp = *(const float4*)&Sj[idx];
    *(float4*)&Sj[idx] = S;
    const float lam = lamC[cidx];
    S.x = lam * S.x + tmp.x;
    S.y = lam * S.y + tmp.y;
    S.z = lam * S.z + tmp.z;
    S.w = lam * S.w + tmp.w;
  }
}

// ---------------- gla_inter: O += qt @ S_j  (per bh,chunk,dv-quarter) -----------
__global__ __launch_bounds__(256, 2)
void gla_inter(const float* __restrict__ qt, const float* __restrict__ Sj,
               float* __restrict__ O)
{
  const int dq = blockIdx.x;
  const int j  = blockIdx.y;
  const int bh = blockIdx.z;
  const int b = bh >> 2, h = bh & 3;
  const int tid = threadIdx.x;
  const int ty = tid >> 4, tx = tid & 15;
  __shared__ __align__(16) float qtS[4224];
  __shared__ __align__(16) float SjS[4224];
  const int tok0 = b * SEQL + j * CHUNK;
  const size_t qkBase = (size_t)tok0 * KDT + h * DKH;
  const size_t sjBase = ((size_t)(bh * NCH + j) * 256) * 512 + dq * 128;
  float acc[8][8];
  #pragma unroll
  for (int i = 0; i < 8; ++i)
    #pragma unroll
    for (int jj = 0; jj < 8; ++jj) acc[i][jj] = 0.f;
  const int sm = tid >> 1, skk = (tid & 1) * 16;
  const int zk = tid >> 3, zc = (tid & 7) * 16;
  for (int dk0 = 0; dk0 < DKH; dk0 += 32) {
    const float4* qg = (const float4*)&qt[qkBase + (size_t)sm * KDT + dk0 + skk];
    float4 q4[4];
    #pragma unroll
    for (int i = 0; i < 4; ++i) q4[i] = qg[i];
    #pragma unroll
    for (int i = 0; i < 4; ++i) {
      qtS[(skk + 4*i + 0)*132 + sm] = q4[i].x;
      qtS[(skk + 4*i + 1)*132 + sm] = q4[i].y;
      qtS[(skk + 4*i + 2)*132 + sm] = q4[i].z;
      qtS[(skk + 4*i + 3)*132 + sm] = q4[i].w;
    }
    {
      const float4* sg = (const float4*)&Sj[sjBase + (size_t)(dk0 + zk) * 512 + zc];
      float4 s4[4];
      #pragma unroll
      for (int i = 0; i < 4; ++i) s4[i] = sg[i];
      #pragma unroll
      for (int i = 0; i < 4; ++i) *(float4*)&SjS[zk*132 + zc + i*4] = s4[i];
    }
    __syncthreads();
    #pragma unroll
    for (int kk = 0; kk < 32; ++kk) {
      const float4 qa = *(const float4*)&qtS[kk*132 + ty*8];
      const float4 qb = *(const float4*)&qtS[kk*132 + ty*8 + 4];
      const float4 sa = *(const float4*)&SjS[kk*132 + tx*8];
      const float4 sb = *(const float4*)&SjS[kk*132 + tx*8 + 4];
      const float qv[8] = {qa.x,qa.y,qa.z,qa.w,qb.x,qb.y,qb.z,qb.w};
      const float sv[8] = {sa.x,sa.y,sa.z,sa.w,sb.x,sb.y,sb.z,sb.w};
      #pragma unroll
      for (int i = 0; i < 8; ++i)
        #pragma unroll
        for (int jj = 0; jj < 8; ++jj)
          acc[i][jj] += qv[i] * sv[jj];
    }
    __syncthreads();
  }
  #pragma unroll
  for (int i = 0; i < 8; ++i) {
    const size_t rb = (size_t)(tok0 + ty*8 + i) * VDT + h * DVH + dq*128 + tx*8;
    float4 o0 = *(const float4*)&O[rb];
    float4 o1 = *(const float4*)&O[rb + 4];
    o0.x += acc[i][0]; o0.y += acc[i][1]; o0.z += acc[i][2]; o0.w += acc[i][3];
    o1.x += acc[i][4]; o1.y += acc[i][5]; o1.z += acc[i][6]; o1.w += acc[i][7];
    *(float4*)&O[rb]     = o0;
    *(float4*)&O[rb + 4] = o1;
  }
}

// ---------------- epilogue: Y(bf16) = RMSNorm(o)*w * silu(g) ----------------
__global__ __launch_bounds__(256)
void epilogue(const float* __restrict__ O, const float* __restrict__ G,
              const float* __restrict__ w, u16* __restrict__ Y)
{
  const int row = blockIdx.x;
  const int tid = threadIdx.x;
  __shared__ float sred[4];
  for (int h = 0; h < NHEADS; ++h) {
    const size_t base = (size_t)row * VDT + h * DVH;
    const float2 o2 = *(const float2*)&O[base + tid * 2];
    float ss = o2.x * o2.x + o2.y * o2.y;
    #pragma unroll
    for (int off = 32; off > 0; off >>= 1) ss += __shfl_down(ss, off);
    if ((tid & 63) == 0) sred[tid >> 6] = ss;
    __syncthreads();
    const float tot = sred[0] + sred[1] + sred[2] + sred[3];
    const float rs = rsqrtf(tot * (1.f / DVH) + 1e-5f);
    const float2 g2 = *(const float2*)&G[base + tid * 2];
    const float2 w2 = *(const float2*)&w[tid * 2];
    const float y0 = o2.x * rs * w2.x * g2.x / (1.f + expf(-g2.x));
    const float y1 = o2.y * rs * w2.y * g2.y / (1.f + expf(-g2.y));
    const u32 pk = (u32)f2bf(y0) | ((u32)f2bf(y1) << 16);
    *(u32*)&Y[base + tid * 2] = pk;
    __syncthreads();
  }
}

extern "C" void kernel_launch(void* const* d_in, const int* in_sizes, int n_in,
                              void* d_out, int out_size, void* d_ws, size_t ws_size,
                              hipStream_t stream)
{
  const float* x    = (const float*)d_in[0];
  const float* Wq   = (const float*)d_in[1];
  const float* Wk   = (const float*)d_in[2];
  const float* Wv   = (const float*)d_in[3];
  const float* Wg   = (const float*)d_in[4];
  const float* gw1  = (const float*)d_in[5];
  const float* gw2  = (const float*)d_in[6];
  const float* gb2  = (const float*)d_in[7];
  const float* gnw  = (const float*)d_in[8];
  const float* Wo   = (const float*)d_in[9];
  float* out = (float*)d_out;

  float* ws = (float*)d_ws;
  const size_t M = 1024ull * 1024ull;
  float* Qb   = ws;               // 4M floats (qt)
  float* Kbf  = ws + 4*M;         // 4M (kt)
  float* EGK  = ws + 8*M;         // 4M (kh)
  float* Vb   = ws + 12*M;        // 8M
  float* Gb   = ws + 20*M;        // 8M
  float* Ob   = ws + 28*M;        // 8M
  float* Sjb  = ws + 36*M;        // 16M (P_j, then in-place chunk-start states)
  float* lamC = ws + 52*M;        // 32K floats
  float* Ub   = ws + 52*M + 32768;  // 64K floats
  // bf16 region (float-slot offsets; 2 u16 per slot)
  u16* xb  = (u16*)(ws + 53*M);             // 4M u16 (2M slots)
  u16* Wqb = (u16*)(ws + 55*M);             // 1M u16
  u16* Wkb = (u16*)(ws + 55*M + 512*1024);  // 1M u16
  u16* Wvb = (u16*)(ws + 56*M);             // 2M u16
  u16* Wgb = (u16*)(ws + 57*M);             // 2M u16
  u16* Wob = (u16*)(ws + 58*M);             // 2M u16
  u16* Y2b = (u16*)Qb;                      // reuses qt after gla_inter

  const float qscale = 0.0625f;   // DK^-0.5

  // fp32 -> bf16 conversions (+ weight transposes to [N][K])
  f2bf_kernel  <<<2048, 256, 0, stream>>>(x, xb, NTOK * DM);
  transpose_f2bf<<<dim3(16, 16), 256, 0, stream>>>(Wq, Wqb, 1024, 1024);
  transpose_f2bf<<<dim3(16, 16), 256, 0, stream>>>(Wk, Wkb, 1024, 1024);
  transpose_f2bf<<<dim3(32, 16), 256, 0, stream>>>(Wv, Wvb, 1024, 2048);
  transpose_f2bf<<<dim3(32, 16), 256, 0, stream>>>(Wg, Wgb, 1024, 2048);
  transpose_f2bf<<<dim3(16, 32), 256, 0, stream>>>(Wo, Wob, 2048, 1024);

  // projections (bf16 MFMA, fp32 out)
  gemm_bf16<<<dim3( 8, 32), 256, 0, stream>>>(xb, Wqb, Qb,  NTOK, 1024, 1024, qscale);
  gemm_bf16<<<dim3( 8, 32), 256, 0, stream>>>(xb, Wkb, Kbf, NTOK, 1024, 1024, 1.f);
  gemm_bf16<<<dim3(16, 32), 256, 0, stream>>>(xb, Wvb, Vb,  NTOK, 2048, 1024, 1.f);
  gemm_bf16<<<dim3(16, 32), 256, 0, stream>>>(xb, Wgb, Gb,  NTOK, 2048, 1024, 1.f);
  gemm_u  <<<64, 256, 0, stream>>>(x, gw1, Ub);
  gate_kernel<<<NTOK, 256, 0, stream>>>(Ub, gw2, gb2, EGK);

  // chunked GLA (fp32)
  chunk_prep<<<dim3(NCH, 8), 256, 0, stream>>>(Qb, Kbf, EGK, lamC);
  gla_intra <<<dim3(2, NCH, 8), 256, 0, stream>>>(Qb, Kbf, Vb, Ob);
  gla_pstate<<<dim3(8, 4, 128), 256, 0, stream>>>(EGK, Vb, Sjb);
  gla_sscan <<<dim3(128, 8), 256, 0, stream>>>(Sjb, lamC);
  gla_inter <<<dim3(4, NCH, 8), 256, 0, stream>>>(Qb, Sjb, Ob);

  // epilogue -> bf16, then output GEMM (bf16 MFMA)
  epilogue<<<NTOK, 256, 0, stream>>>(Ob, Gb, gnw, Y2b);
  gemm_bf16<<<dim3(8, 32), 256, 0, stream>>>(Y2b, Wob, out, NTOK, 1024, 2048, 1.f);
}

// Round 6
// 356.516 us; speedup vs baseline: 7.8564x; 1.3454x over previous
//
#include <hip/hip_runtime.h>
#include <hip/hip_bf16.h>
#include <math.h>

#define NHEADS 4
#define DKH 256
#define DVH 512
#define SEQL 2048
#define NB 2
#define NTOK (NB*SEQL)     // 4096
#define DM 1024            // d_model
#define KDT 1024           // NHEADS*DKH
#define VDT 2048           // NHEADS*DVH
#define CHUNK 128
#define NCH (SEQL/CHUNK)   // 16

typedef unsigned short u16;
typedef unsigned int   u32;
typedef unsigned long long u64;
typedef __attribute__((ext_vector_type(8))) short bf16x8;
typedef __attribute__((ext_vector_type(4))) float f32x4;

__device__ inline u16 f2bf(float f) {
  __hip_bfloat16 h = __float2bfloat16(f);
  return *reinterpret_cast<u16*>(&h);
}
__device__ inline float bf2f(u16 u) {
  u32 x = ((u32)u) << 16;
  return __uint_as_float(x);
}

// ---------------- fp32 -> bf16 elementwise ----------------
__global__ __launch_bounds__(256)
void f2bf_kernel(const float* __restrict__ in, u16* __restrict__ out, int n)
{
  const int i = (blockIdx.x * 256 + threadIdx.x) * 8;
  if (i >= n) return;
  const float4 x0 = *(const float4*)&in[i];
  const float4 x1 = *(const float4*)&in[i + 4];
  int4 p;
  p.x = f2bf(x0.x) | ((u32)f2bf(x0.y) << 16);
  p.y = f2bf(x0.z) | ((u32)f2bf(x0.w) << 16);
  p.z = f2bf(x1.x) | ((u32)f2bf(x1.y) << 16);
  p.w = f2bf(x1.z) | ((u32)f2bf(x1.w) << 16);
  *(int4*)&out[i] = p;
}

// ---------------- W[K][N] fp32 -> Wt[N][K] bf16 ---------------
__global__ __launch_bounds__(256)
void transpose_f2bf(const float* __restrict__ W, u16* __restrict__ Wt, int K, int N)
{
  __shared__ float Ts[64][69];
  const int n0 = blockIdx.x * 64, k0 = blockIdx.y * 64;
  const int tx = threadIdx.x & 15, ty = threadIdx.x >> 4;
  #pragma unroll
  for (int r = 0; r < 4; ++r) {
    const int k = ty + r * 16;
    const float4 w4 = *(const float4*)&W[(size_t)(k0 + k) * N + n0 + tx * 4];
    Ts[tx*4 + 0][k] = w4.x;
    Ts[tx*4 + 1][k] = w4.y;
    Ts[tx*4 + 2][k] = w4.z;
    Ts[tx*4 + 3][k] = w4.w;
  }
  __syncthreads();
  #pragma unroll
  for (int r = 0; r < 4; ++r) {
    const int n = ty + r * 16;
    u64 pk = (u64)f2bf(Ts[n][tx*4 + 0]) | ((u64)f2bf(Ts[n][tx*4 + 1]) << 16)
           | ((u64)f2bf(Ts[n][tx*4 + 2]) << 32) | ((u64)f2bf(Ts[n][tx*4 + 3]) << 48);
    *(u64*)&Wt[(size_t)(n0 + n) * K + k0 + tx * 4] = pk;
  }
}

// ---------------- bf16 MFMA GEMM: C = scale*(A[M][K] @ Bt[N][K]^T), fp32 out ----
// 128x128 tile, 4 waves, 16x16x32 MFMA, BK=32. LDS stride 40 (de-conflicted).
__global__ __launch_bounds__(256)
void gemm_bf16(const u16* __restrict__ A, const u16* __restrict__ Bt,
               float* __restrict__ C, int M, int N, int K, float scale)
{
  __shared__ __align__(16) u16 As[128 * 40];
  __shared__ __align__(16) u16 Bs[128 * 40];
  const int tid = threadIdx.x;
  const int lane = tid & 63, wave = tid >> 6;
  const int wr = wave >> 1, wc = wave & 1;
  const int l15 = lane & 15, l4 = lane >> 4;
  const int bm = blockIdx.y * 128, bn = blockIdx.x * 128;

  f32x4 acc[4][4];
  #pragma unroll
  for (int i = 0; i < 4; ++i)
    #pragma unroll
    for (int j = 0; j < 4; ++j)
      acc[i][j] = (f32x4){0.f, 0.f, 0.f, 0.f};

  const int srow = tid >> 2;
  const int scol = (tid & 3) * 8;
  const u16* Ag = &A [(size_t)(bm + srow) * K + scol];
  const u16* Bg = &Bt[(size_t)(bn + srow) * K + scol];

  int4 a0 = *(const int4*)(Ag);
  int4 a1 = *(const int4*)(Ag + (size_t)64 * K);
  int4 b0 = *(const int4*)(Bg);
  int4 b1 = *(const int4*)(Bg + (size_t)64 * K);

  for (int k0 = 0; k0 < K; k0 += 32) {
    __syncthreads();
    *(int4*)&As[(srow)      * 40 + scol] = a0;
    *(int4*)&As[(64 + srow) * 40 + scol] = a1;
    *(int4*)&Bs[(srow)      * 40 + scol] = b0;
    *(int4*)&Bs[(64 + srow) * 40 + scol] = b1;
    __syncthreads();
    if (k0 + 32 < K) {
      a0 = *(const int4*)(Ag + k0 + 32);
      a1 = *(const int4*)(Ag + (size_t)64 * K + k0 + 32);
      b0 = *(const int4*)(Bg + k0 + 32);
      b1 = *(const int4*)(Bg + (size_t)64 * K + k0 + 32);
    }
    bf16x8 af[4], bfv[4];
    #pragma unroll
    for (int mi = 0; mi < 4; ++mi)
      af[mi] = *(const bf16x8*)&As[(wr*64 + mi*16 + l15) * 40 + l4*8];
    #pragma unroll
    for (int ni = 0; ni < 4; ++ni)
      bfv[ni] = *(const bf16x8*)&Bs[(wc*64 + ni*16 + l15) * 40 + l4*8];
    #pragma unroll
    for (int mi = 0; mi < 4; ++mi)
      #pragma unroll
      for (int ni = 0; ni < 4; ++ni)
        acc[mi][ni] = __builtin_amdgcn_mfma_f32_16x16x32_bf16(af[mi], bfv[ni], acc[mi][ni], 0, 0, 0);
  }

  #pragma unroll
  for (int mi = 0; mi < 4; ++mi)
    #pragma unroll
    for (int ni = 0; ni < 4; ++ni) {
      const int col = bn + wc*64 + ni*16 + l15;
      #pragma unroll
      for (int r = 0; r < 4; ++r) {
        const int row = bm + wr*64 + mi*16 + l4*4 + r;
        C[(size_t)row * N + col] = acc[mi][ni][r] * scale;
      }
    }
}

// ---------------- V projection -> Vt bf16 transposed [bh*512+dv][L] -------------
__global__ __launch_bounds__(256)
void gemm_bf16_vt(const u16* __restrict__ A, const u16* __restrict__ Bt,
                  u16* __restrict__ Vt, int M, int N, int K)
{
  __shared__ __align__(16) u16 As[128 * 40];
  __shared__ __align__(16) u16 Bs[128 * 40];
  const int tid = threadIdx.x;
  const int lane = tid & 63, wave = tid >> 6;
  const int wr = wave >> 1, wc = wave & 1;
  const int l15 = lane & 15, l4 = lane >> 4;
  const int bm = blockIdx.y * 128, bn = blockIdx.x * 128;

  f32x4 acc[4][4];
  #pragma unroll
  for (int i = 0; i < 4; ++i)
    #pragma unroll
    for (int j = 0; j < 4; ++j)
      acc[i][j] = (f32x4){0.f, 0.f, 0.f, 0.f};

  const int srow = tid >> 2;
  const int scol = (tid & 3) * 8;
  const u16* Ag = &A [(size_t)(bm + srow) * K + scol];
  const u16* Bg = &Bt[(size_t)(bn + srow) * K + scol];

  int4 a0 = *(const int4*)(Ag);
  int4 a1 = *(const int4*)(Ag + (size_t)64 * K);
  int4 b0 = *(const int4*)(Bg);
  int4 b1 = *(const int4*)(Bg + (size_t)64 * K);

  for (int k0 = 0; k0 < K; k0 += 32) {
    __syncthreads();
    *(int4*)&As[(srow)      * 40 + scol] = a0;
    *(int4*)&As[(64 + srow) * 40 + scol] = a1;
    *(int4*)&Bs[(srow)      * 40 + scol] = b0;
    *(int4*)&Bs[(64 + srow) * 40 + scol] = b1;
    __syncthreads();
    if (k0 + 32 < K) {
      a0 = *(const int4*)(Ag + k0 + 32);
      a1 = *(const int4*)(Ag + (size_t)64 * K + k0 + 32);
      b0 = *(const int4*)(Bg + k0 + 32);
      b1 = *(const int4*)(Bg + (size_t)64 * K + k0 + 32);
    }
    bf16x8 af[4], bfv[4];
    #pragma unroll
    for (int mi = 0; mi < 4; ++mi)
      af[mi] = *(const bf16x8*)&As[(wr*64 + mi*16 + l15) * 40 + l4*8];
    #pragma unroll
    for (int ni = 0; ni < 4; ++ni)
      bfv[ni] = *(const bf16x8*)&Bs[(wc*64 + ni*16 + l15) * 40 + l4*8];
    #pragma unroll
    for (int mi = 0; mi < 4; ++mi)
      #pragma unroll
      for (int ni = 0; ni < 4; ++ni)
        acc[mi][ni] = __builtin_amdgcn_mfma_f32_16x16x32_bf16(af[mi], bfv[ni], acc[mi][ni], 0, 0, 0);
  }

  // store transposed: Vt[(b*4+h)*512 + dv][l], 4 consecutive l per lane -> u64
  #pragma unroll
  for (int mi = 0; mi < 4; ++mi) {
    const int row0 = bm + wr*64 + mi*16 + l4*4;   // token
    const int b = row0 >> 11, l = row0 & 2047;
    #pragma unroll
    for (int ni = 0; ni < 4; ++ni) {
      const int col = bn + wc*64 + ni*16 + l15;   // n = h*512 + dv
      const int h = col >> 9, dv = col & 511;
      u64 pk = (u64)f2bf(acc[mi][ni][0]) | ((u64)f2bf(acc[mi][ni][1]) << 16)
             | ((u64)f2bf(acc[mi][ni][2]) << 32) | ((u64)f2bf(acc[mi][ni][3]) << 48);
      *(u64*)&Vt[((size_t)((b*4 + h)*512 + dv)) * SEQL + l] = pk;
    }
  }
}

// ---------------- U = x @ gk_w1 ----------------
__global__ __launch_bounds__(256)
void gemm_u(const float* __restrict__ X, const float* __restrict__ W1,
            float* __restrict__ U)
{
  __shared__ float Xs[64][65];
  __shared__ __align__(16) float W1s[64][16];
  const int tid = threadIdx.x;
  const int row0 = blockIdx.x * 64;
  const int rr = tid & 63, gg = tid >> 6;
  float acc[4] = {0.f, 0.f, 0.f, 0.f};
  for (int k0 = 0; k0 < DM; k0 += 64) {
    #pragma unroll
    for (int rep = 0; rep < 4; ++rep) {
      const int m = (tid >> 4) + rep * 16;
      const int kk = (tid & 15) << 2;
      const float4 x4 = *(const float4*)&X[(size_t)(row0 + m) * DM + k0 + kk];
      Xs[kk+0][m] = x4.x; Xs[kk+1][m] = x4.y; Xs[kk+2][m] = x4.z; Xs[kk+3][m] = x4.w;
    }
    {
      const int kk = tid >> 2, n = (tid & 3) << 2;
      *(float4*)&W1s[kk][n] = *(const float4*)&W1[(size_t)(k0 + kk) * 16 + n];
    }
    __syncthreads();
    #pragma unroll
    for (int k2 = 0; k2 < 64; ++k2) {
      const float xv = Xs[k2][rr];
      const float4 w4 = *(const float4*)&W1s[k2][gg << 2];
      acc[0] += xv * w4.x; acc[1] += xv * w4.y; acc[2] += xv * w4.z; acc[3] += xv * w4.w;
    }
    __syncthreads();
  }
  *(float4*)&U[(size_t)(row0 + rr) * 16 + (gg << 2)] =
      make_float4(acc[0], acc[1], acc[2], acc[3]);
}

// ---------------- EG = exp(log_sigmoid(U @ gk_w2 + b2) / 16) ----------------
__device__ inline float ls_exp(float z) {
  const float ls = (z >= 0.f) ? -log1pf(expf(-z)) : (z - log1pf(expf(z)));
  return expf(ls * 0.0625f);
}

__global__ __launch_bounds__(256)
void gate_kernel(const float* __restrict__ U, const float* __restrict__ W2,
                 const float* __restrict__ b2, float* __restrict__ EGKo)
{
  __shared__ float Us[16];
  const int row = blockIdx.x, tid = threadIdx.x;
  if (tid < 16) Us[tid] = U[row * 16 + tid];
  __syncthreads();
  const int d0 = tid << 2;
  float4 z = *(const float4*)&b2[d0];
  #pragma unroll
  for (int r = 0; r < 16; ++r) {
    const float u = Us[r];
    const float4 w4 = *(const float4*)&W2[r * 1024 + d0];
    z.x += u * w4.x; z.y += u * w4.y; z.z += u * w4.z; z.w += u * w4.w;
  }
  float4 e = make_float4(ls_exp(z.x), ls_exp(z.y), ls_exp(z.z), ls_exp(z.w));
  *(float4*)&EGKo[(size_t)row * 1024 + d0] = e;
}

// ---------------- chunk_prep: bf16 qt=q*Lam, kt=k/Lam, kh=kt*LamC; lamC ---------
__global__ __launch_bounds__(256)
void chunk_prep(const float* __restrict__ Q, const float* __restrict__ K,
                const float* __restrict__ EG, u16* __restrict__ qtb,
                u16* __restrict__ ktb, u16* __restrict__ khb,
                float* __restrict__ lamC)
{
  const int j = blockIdx.x;
  const int bh = blockIdx.y;
  const int b = bh >> 2, h = bh & 3;
  const int tid = threadIdx.x;   // dk lane
  const size_t base = ((size_t)(b * SEQL + j * CHUNK)) * KDT + h * DKH + tid;
  float cum = 1.f;
  for (int t = 0; t < CHUNK; t += 4) {
    const size_t i0 = base + (size_t)t * KDT;
    float d[4], q[4], k[4];
    #pragma unroll
    for (int u = 0; u < 4; ++u) {
      d[u] = EG[i0 + (size_t)u * KDT];
      q[u] = Q [i0 + (size_t)u * KDT];
      k[u] = K [i0 + (size_t)u * KDT];
    }
    #pragma unroll
    for (int u = 0; u < 4; ++u) {
      cum *= d[u];
      qtb[i0 + (size_t)u * KDT] = f2bf(q[u] * cum);
      ktb[i0 + (size_t)u * KDT] = f2bf(k[u] / cum);
    }
  }
  lamC[(bh * NCH + j) * 256 + tid] = cum;
  for (int t = 0; t < CHUNK; t += 4) {
    const size_t i0 = base + (size_t)t * KDT;
    u16 kt4[4];
    #pragma unroll
    for (int u = 0; u < 4; ++u) kt4[u] = ktb[i0 + (size_t)u * KDT];
    #pragma unroll
    for (int u = 0; u < 4; ++u)
      khb[i0 + (size_t)u * KDT] = f2bf(bf2f(kt4[u]) * cum);
  }
}

// ---------------- gla_intra_mfma: O = tril(qt@kt^T) @ V  (MFMA) -----------------
// grid (2 dv-halves, NCH, 8 bh); 4 waves 2x2.
__global__ __launch_bounds__(256)
void gla_intra_mfma(const u16* __restrict__ qt, const u16* __restrict__ kt,
                    const u16* __restrict__ Vt, float* __restrict__ O)
{
  const int half = blockIdx.x;
  const int j    = blockIdx.y;
  const int bh   = blockIdx.z;
  const int b = bh >> 2, h = bh & 3;
  const int tid = threadIdx.x;
  const int lane = tid & 63, wave = tid >> 6;
  const int wr = wave >> 1, wc = wave & 1;
  const int l15 = lane & 15, l4 = lane >> 4;
  const int tok0 = b * SEQL + j * CHUNK;

  __shared__ __align__(16) u16 Pl[128 * 136];   // masked P bf16 [t][s]
  __shared__ __align__(16) u16 Bl[128 * 136];   // PV B [dv][s]; aliases QK staging
  u16* As = Bl;                // [128][40]
  u16* Bs = Bl + 128 * 40;     // [128][40]

  const size_t qkBase = (size_t)tok0 * KDT + h * DKH;

  f32x4 acc[4][4];
  #pragma unroll
  for (int i = 0; i < 4; ++i)
    #pragma unroll
    for (int jj = 0; jj < 4; ++jj) acc[i][jj] = (f32x4){0.f,0.f,0.f,0.f};

  const int srow = tid >> 2, scol = (tid & 3) * 8;
  for (int dk0 = 0; dk0 < DKH; dk0 += 32) {
    *(int4*)&As[(srow)    * 40 + scol] = *(const int4*)&qt[qkBase + (size_t)srow      * KDT + dk0 + scol];
    *(int4*)&As[(64+srow) * 40 + scol] = *(const int4*)&qt[qkBase + (size_t)(64+srow) * KDT + dk0 + scol];
    *(int4*)&Bs[(srow)    * 40 + scol] = *(const int4*)&kt[qkBase + (size_t)srow      * KDT + dk0 + scol];
    *(int4*)&Bs[(64+srow) * 40 + scol] = *(const int4*)&kt[qkBase + (size_t)(64+srow) * KDT + dk0 + scol];
    __syncthreads();
    bf16x8 af[4], bv[4];
    #pragma unroll
    for (int mi = 0; mi < 4; ++mi)
      af[mi] = *(const bf16x8*)&As[(wr*64 + mi*16 + l15) * 40 + l4*8];
    #pragma unroll
    for (int ni = 0; ni < 4; ++ni)
      bv[ni] = *(const bf16x8*)&Bs[(wc*64 + ni*16 + l15) * 40 + l4*8];
    #pragma unroll
    for (int mi = 0; mi < 4; ++mi)
      #pragma unroll
      for (int ni = 0; ni < 4; ++ni)
        acc[mi][ni] = __builtin_amdgcn_mfma_f32_16x16x32_bf16(af[mi], bv[ni], acc[mi][ni], 0, 0, 0);
    __syncthreads();
  }

  // mask -> Pl bf16 [t][s]
  #pragma unroll
  for (int mi = 0; mi < 4; ++mi)
    #pragma unroll
    for (int ni = 0; ni < 4; ++ni) {
      const int s = wc*64 + ni*16 + l15;
      #pragma unroll
      for (int r = 0; r < 4; ++r) {
        const int t = wr*64 + mi*16 + l4*4 + r;
        Pl[t*136 + s] = (s <= t) ? f2bf(acc[mi][ni][r]) : (u16)0;
      }
    }
  __syncthreads();

  // PV over two 128-dv tiles
  for (int dt = 0; dt < 2; ++dt) {
    #pragma unroll
    for (int i = 0; i < 8; ++i) {
      const int row = i*16 + (tid >> 4);
      const int col8 = (tid & 15) * 8;
      *(int4*)&Bl[row*136 + col8] =
        *(const int4*)&Vt[((size_t)(bh*512 + half*256 + dt*128 + row)) * SEQL + j*CHUNK + col8];
    }
    __syncthreads();
    f32x4 acc2[4][4];
    #pragma unroll
    for (int i = 0; i < 4; ++i)
      #pragma unroll
      for (int jj = 0; jj < 4; ++jj) acc2[i][jj] = (f32x4){0.f,0.f,0.f,0.f};
    #pragma unroll
    for (int ks = 0; ks < 4; ++ks) {
      bf16x8 af2[4], bv2[4];
      #pragma unroll
      for (int mi = 0; mi < 4; ++mi)
        af2[mi] = *(const bf16x8*)&Pl[(wr*64 + mi*16 + l15)*136 + ks*32 + l4*8];
      #pragma unroll
      for (int ni = 0; ni < 4; ++ni)
        bv2[ni] = *(const bf16x8*)&Bl[(wc*64 + ni*16 + l15)*136 + ks*32 + l4*8];
      #pragma unroll
      for (int mi = 0; mi < 4; ++mi)
        #pragma unroll
        for (int ni = 0; ni < 4; ++ni)
          acc2[mi][ni] = __builtin_amdgcn_mfma_f32_16x16x32_bf16(af2[mi], bv2[ni], acc2[mi][ni], 0, 0, 0);
    }
    #pragma unroll
    for (int mi = 0; mi < 4; ++mi)
      #pragma unroll
      for (int ni = 0; ni < 4; ++ni) {
        const int col = h*DVH + half*256 + dt*128 + wc*64 + ni*16 + l15;
        #pragma unroll
        for (int r = 0; r < 4; ++r) {
          const int row = tok0 + wr*64 + mi*16 + l4*4 + r;
          O[(size_t)row * VDT + col] = acc2[mi][ni][r];
        }
      }
    __syncthreads();
  }
}

// ---------------- gla_pstate_mfma: P^T[dv][dk] = Vt_j @ kh_j  (MFMA) ------------
// grid (4 dv-tiles, 2 dk-tiles, 128 jc)
__global__ __launch_bounds__(256)
void gla_pstate_mfma(const u16* __restrict__ kh, const u16* __restrict__ Vt,
                     float* __restrict__ P)
{
  const int mb = blockIdx.x, nb = blockIdx.y, jc = blockIdx.z;
  const int bh = jc >> 4, j = jc & 15;
  const int b = bh >> 2, h = bh & 3;
  const int tid = threadIdx.x;
  const int lane = tid & 63, wave = tid >> 6;
  const int wr = wave >> 1, wc = wave & 1;
  const int l15 = lane & 15, l4 = lane >> 4;
  const int tok0 = b * SEQL + j * CHUNK;

  __shared__ __align__(16) u16 Al[128 * 40];   // Vt [dv][t]
  __shared__ __align__(16) u16 Blt[128 * 40];  // kh^T [dk][t]

  f32x4 acc[4][4];
  #pragma unroll
  for (int i = 0; i < 4; ++i)
    #pragma unroll
    for (int jj = 0; jj < 4; ++jj) acc[i][jj] = (f32x4){0.f,0.f,0.f,0.f};

  for (int kt0 = 0; kt0 < CHUNK; kt0 += 32) {
    {
      const int srow = tid >> 2, scol = (tid & 3) * 8;
      *(int4*)&Al[(srow)    * 40 + scol] =
        *(const int4*)&Vt[((size_t)(bh*512 + mb*128 + srow))    * SEQL + j*CHUNK + kt0 + scol];
      *(int4*)&Al[(64+srow) * 40 + scol] =
        *(const int4*)&Vt[((size_t)(bh*512 + mb*128 + 64+srow)) * SEQL + j*CHUNK + kt0 + scol];
    }
    {
      const int t = tid & 31;
      #pragma unroll
      for (int i = 0; i < 2; ++i) {
        const int dkg = (tid >> 5) * 16 + i * 8;
        int4 v = *(const int4*)&kh[(size_t)(tok0 + kt0 + t) * KDT + h*DKH + nb*128 + dkg];
        const u16* pv = (const u16*)&v;
        #pragma unroll
        for (int u = 0; u < 8; ++u) Blt[(dkg + u)*40 + t] = pv[u];
      }
    }
    __syncthreads();
    bf16x8 af[4], bv[4];
    #pragma unroll
    for (int mi = 0; mi < 4; ++mi)
      af[mi] = *(const bf16x8*)&Al[(wr*64 + mi*16 + l15)*40 + l4*8];
    #pragma unroll
    for (int ni = 0; ni < 4; ++ni)
      bv[ni] = *(const bf16x8*)&Blt[(wc*64 + ni*16 + l15)*40 + l4*8];
    #pragma unroll
    for (int mi = 0; mi < 4; ++mi)
      #pragma unroll
      for (int ni = 0; ni < 4; ++ni)
        acc[mi][ni] = __builtin_amdgcn_mfma_f32_16x16x32_bf16(af[mi], bv[ni], acc[mi][ni], 0, 0, 0);
    __syncthreads();
  }

  #pragma unroll
  for (int mi = 0; mi < 4; ++mi)
    #pragma unroll
    for (int ni = 0; ni < 4; ++ni) {
      const int col = nb*128 + wc*64 + ni*16 + l15;   // dk
      #pragma unroll
      for (int r = 0; r < 4; ++r) {
        const int row = mb*128 + wr*64 + mi*16 + l4*4 + r;  // dv
        P[(size_t)jc * 131072 + (size_t)row * 256 + col] = acc[mi][ni][r];
      }
    }
}

// ---------------- gla_sscan: S^T recurrence, bf16 SjT out -----------------------
// grid (128, 8). S stored per chunk-start: SjT[jc][dv][dk] bf16.
__global__ __launch_bounds__(256)
void gla_sscan(const float* __restrict__ P, const float* __restrict__ lamC,
               u16* __restrict__ SjT)
{
  const int bh = blockIdx.y;
  const int e0 = blockIdx.x * 1024 + threadIdx.x * 4;
  const int dv = e0 >> 8, dk = e0 & 255;
  float4 S = make_float4(0.f, 0.f, 0.f, 0.f);
  for (int j = 0; j < NCH; ++j) {
    const size_t cb = (size_t)(bh * NCH + j);
    const float4 lam = *(const float4*)&lamC[cb * 256 + dk];
    const size_t idx = cb * 131072 + (size_t)dv * 256 + dk;
    const float4 tmp = *(const float4*)&P[idx];
    u64 pk = (u64)f2bf(S.x) | ((u64)f2bf(S.y) << 16)
           | ((u64)f2bf(S.z) << 32) | ((u64)f2bf(S.w) << 48);
    *(u64*)&SjT[idx] = pk;
    S.x = lam.x * S.x + tmp.x;
    S.y = lam.y * S.y + tmp.y;
    S.z = lam.z * S.z + tmp.z;
    S.w = lam.w * S.w + tmp.w;
  }
}

// ---------------- gla_inter_mfma: O += qt @ S_j  (MFMA) -------------------------
// grid (4 dv-tiles, NCH, 8 bh); K=256 dk.
__global__ __launch_bounds__(256)
void gla_inter_mfma(const u16* __restrict__ qt, const u16* __restrict__ SjT,
                    float* __restrict__ O)
{
  const int dq = blockIdx.x, j = blockIdx.y, bh = blockIdx.z;
  const int b = bh >> 2, h = bh & 3;
  const int tid = threadIdx.x;
  const int lane = tid & 63, wave = tid >> 6;
  const int wr = wave >> 1, wc = wave & 1;
  const int l15 = lane & 15, l4 = lane >> 4;
  const int tok0 = b * SEQL + j * CHUNK;

  __shared__ __align__(16) u16 As[128 * 40];
  __shared__ __align__(16) u16 Bs[128 * 40];

  const size_t aBase = (size_t)tok0 * KDT + h * DKH;
  const size_t sBase = (size_t)(bh * NCH + j) * 131072 + (size_t)dq * 128 * 256;

  f32x4 acc[4][4];
  #pragma unroll
  for (int i = 0; i < 4; ++i)
    #pragma unroll
    for (int jj = 0; jj < 4; ++jj) acc[i][jj] = (f32x4){0.f,0.f,0.f,0.f};

  const int srow = tid >> 2, scol = (tid & 3) * 8;
  for (int k0 = 0; k0 < DKH; k0 += 32) {
    *(int4*)&As[(srow)    * 40 + scol] = *(const int4*)&qt [aBase + (size_t)srow      * KDT + k0 + scol];
    *(int4*)&As[(64+srow) * 40 + scol] = *(const int4*)&qt [aBase + (size_t)(64+srow) * KDT + k0 + scol];
    *(int4*)&Bs[(srow)    * 40 + scol] = *(const int4*)&SjT[sBase + (size_t)srow      * 256 + k0 + scol];
    *(int4*)&Bs[(64+srow) * 40 + scol] = *(const int4*)&SjT[sBase + (size_t)(64+srow) * 256 + k0 + scol];
    __syncthreads();
    bf16x8 af[4], bv[4];
    #pragma unroll
    for (int mi = 0; mi < 4; ++mi)
      af[mi] = *(const bf16x8*)&As[(wr*64 + mi*16 + l15)*40 + l4*8];
    #pragma unroll
    for (int ni = 0; ni < 4; ++ni)
      bv[ni] = *(const bf16x8*)&Bs[(wc*64 + ni*16 + l15)*40 + l4*8];
    #pragma unroll
    for (int mi = 0; mi < 4; ++mi)
      #pragma unroll
      for (int ni = 0; ni < 4; ++ni)
        acc[mi][ni] = __builtin_amdgcn_mfma_f32_16x16x32_bf16(af[mi], bv[ni], acc[mi][ni], 0, 0, 0);
    __syncthreads();
  }

  #pragma unroll
  for (int mi = 0; mi < 4; ++mi)
    #pragma unroll
    for (int ni = 0; ni < 4; ++ni) {
      const int col = h*DVH + dq*128 + wc*64 + ni*16 + l15;
      #pragma unroll
      for (int r = 0; r < 4; ++r) {
        const int row = tok0 + wr*64 + mi*16 + l4*4 + r;
        float* po = &O[(size_t)row * VDT + col];
        *po += acc[mi][ni][r];
      }
    }
}

// ---------------- epilogue: Y(bf16) = RMSNorm(o)*w * silu(g) ----------------
__global__ __launch_bounds__(256)
void epilogue(const float* __restrict__ O, const float* __restrict__ G,
              const float* __restrict__ w, u16* __restrict__ Y)
{
  const int row = blockIdx.x;
  const int tid = threadIdx.x;
  __shared__ float sred[4];
  for (int h = 0; h < NHEADS; ++h) {
    const size_t base = (size_t)row * VDT + h * DVH;
    const float2 o2 = *(const float2*)&O[base + tid * 2];
    float ss = o2.x * o2.x + o2.y * o2.y;
    #pragma unroll
    for (int off = 32; off > 0; off >>= 1) ss += __shfl_down(ss, off);
    if ((tid & 63) == 0) sred[tid >> 6] = ss;
    __syncthreads();
    const float tot = sred[0] + sred[1] + sred[2] + sred[3];
    const float rs = rsqrtf(tot * (1.f / DVH) + 1e-5f);
    const float2 g2 = *(const float2*)&G[base + tid * 2];
    const float2 w2 = *(const float2*)&w[tid * 2];
    const float y0 = o2.x * rs * w2.x * g2.x / (1.f + expf(-g2.x));
    const float y1 = o2.y * rs * w2.y * g2.y / (1.f + expf(-g2.y));
    const u32 pk = (u32)f2bf(y0) | ((u32)f2bf(y1) << 16);
    *(u32*)&Y[base + tid * 2] = pk;
    __syncthreads();
  }
}

extern "C" void kernel_launch(void* const* d_in, const int* in_sizes, int n_in,
                              void* d_out, int out_size, void* d_ws, size_t ws_size,
                              hipStream_t stream)
{
  const float* x    = (const float*)d_in[0];
  const float* Wq   = (const float*)d_in[1];
  const float* Wk   = (const float*)d_in[2];
  const float* Wv   = (const float*)d_in[3];
  const float* Wg   = (const float*)d_in[4];
  const float* gw1  = (const float*)d_in[5];
  const float* gw2  = (const float*)d_in[6];
  const float* gb2  = (const float*)d_in[7];
  const float* gnw  = (const float*)d_in[8];
  const float* Wo   = (const float*)d_in[9];
  float* out = (float*)d_out;

  float* ws = (float*)d_ws;
  const size_t M = 1024ull * 1024ull;
  float* Qb   = ws;                 // fp32 Q out (dead after chunk_prep; Y2b reuses)
  float* Kbf  = ws + 4*M;           // fp32 K out (dead after chunk_prep; Wob reuses)
  float* EGK  = ws + 8*M;           // fp32 per-step decay (dead after chunk_prep; SjT reuses)
  u16*   Vtb  = (u16*)(ws + 12*M);  // bf16 transposed V [4096 rows][2048]
  u16*   qtb  = (u16*)(ws + 16*M);  // bf16 qt
  u16*   ktb  = (u16*)(ws + 18*M);  // bf16 kt
  float* Gb   = ws + 20*M;          // fp32 gate input G
  float* Ob   = ws + 28*M;          // fp32 attention output
  float* Sjb  = ws + 36*M;          // fp32 P^T per chunk
  float* lamC = ws + 52*M;          // 32K floats
  float* Ub   = ws + 52*M + 32768;  // 64K floats
  u16*   khb  = (u16*)(ws + 53*M);  // bf16 kh
  u16*   xb   = (u16*)(ws + 55*M);
  u16*   Wqb  = (u16*)(ws + 57*M);
  u16*   Wkb  = (u16*)(ws + 57*M + 512*1024);
  u16*   Wvb  = (u16*)(ws + 58*M);
  u16*   Wgb  = (u16*)(ws + 59*M);
  u16*   Wob  = (u16*)Kbf;          // after chunk_prep
  u16*   SjTb = (u16*)EGK;          // after chunk_prep
  u16*   Y2b  = (u16*)Qb;           // after chunk_prep

  const float qscale = 0.0625f;     // DK^-0.5

  f2bf_kernel  <<<2048, 256, 0, stream>>>(x, xb, NTOK * DM);
  transpose_f2bf<<<dim3(16, 16), 256, 0, stream>>>(Wq, Wqb, 1024, 1024);
  transpose_f2bf<<<dim3(16, 16), 256, 0, stream>>>(Wk, Wkb, 1024, 1024);
  transpose_f2bf<<<dim3(32, 16), 256, 0, stream>>>(Wv, Wvb, 1024, 2048);
  transpose_f2bf<<<dim3(32, 16), 256, 0, stream>>>(Wg, Wgb, 1024, 2048);

  gemm_bf16   <<<dim3( 8, 32), 256, 0, stream>>>(xb, Wqb, Qb,  NTOK, 1024, 1024, qscale);
  gemm_bf16   <<<dim3( 8, 32), 256, 0, stream>>>(xb, Wkb, Kbf, NTOK, 1024, 1024, 1.f);
  gemm_bf16_vt<<<dim3(16, 32), 256, 0, stream>>>(xb, Wvb, Vtb, NTOK, 2048, 1024);
  gemm_bf16   <<<dim3(16, 32), 256, 0, stream>>>(xb, Wgb, Gb,  NTOK, 2048, 1024, 1.f);
  gemm_u      <<<64, 256, 0, stream>>>(x, gw1, Ub);
  gate_kernel <<<NTOK, 256, 0, stream>>>(Ub, gw2, gb2, EGK);

  chunk_prep<<<dim3(NCH, 8), 256, 0, stream>>>(Qb, Kbf, EGK, qtb, ktb, khb, lamC);

  // Wo transpose into the (now dead) fp32-K region
  transpose_f2bf<<<dim3(16, 32), 256, 0, stream>>>(Wo, Wob, 2048, 1024);

  gla_intra_mfma <<<dim3(2, NCH, 8), 256, 0, stream>>>(qtb, ktb, Vtb, Ob);
  gla_pstate_mfma<<<dim3(4, 2, 128), 256, 0, stream>>>(khb, Vtb, Sjb);
  gla_sscan      <<<dim3(128, 8), 256, 0, stream>>>(Sjb, lamC, SjTb);
  gla_inter_mfma <<<dim3(4, NCH, 8), 256, 0, stream>>>(qtb, SjTb, Ob);

  epilogue<<<NTOK, 256, 0, stream>>>(Ob, Gb, gnw, Y2b);
  gemm_bf16<<<dim3(8, 32), 256, 0, stream>>>(Y2b, Wob, out, NTOK, 1024, 2048, 1.f);
}